// Round 1
// baseline (2586.718 us; speedup 1.0000x reference)
//
#include <hip/hip_runtime.h>

#define NH 96
#define NH2 192

// ---------------- CSR build ----------------

__global__ void k_count(const int* __restrict__ dst1, const int* __restrict__ dst2,
                        int* __restrict__ cnt1, int* __restrict__ cnt2, int E) {
  int e = blockIdx.x * blockDim.x + threadIdx.x;
  if (e < E) {
    atomicAdd(&cnt1[dst1[e]], 1);
    atomicAdd(&cnt2[dst2[e]], 1);
  }
}

__global__ __launch_bounds__(1024) void k_scan(const int* __restrict__ cnt, int* __restrict__ rp, int n) {
  __shared__ int s[1024];
  int tid = threadIdx.x;
  int chunk = (n + 1023) >> 10;
  int beg = tid * chunk;
  int end = min(beg + chunk, n);
  int sum = 0;
  for (int i = beg; i < end; ++i) sum += cnt[i];
  s[tid] = sum;
  __syncthreads();
  for (int off = 1; off < 1024; off <<= 1) {
    int v = (tid >= off) ? s[tid - off] : 0;
    __syncthreads();
    s[tid] += v;
    __syncthreads();
  }
  int excl = (tid == 0) ? 0 : s[tid - 1];
  for (int i = beg; i < end; ++i) { rp[i] = excl; excl += cnt[i]; }
  if (tid == 1023) rp[n] = s[1023];
}

__global__ void k_scatter(const int* __restrict__ d1, const int* __restrict__ s1, const float* __restrict__ v1,
                          const int* __restrict__ rp1, int* __restrict__ cur1,
                          int* __restrict__ c1s, float* __restrict__ c1v,
                          const int* __restrict__ s2, const int* __restrict__ d2,
                          const int* __restrict__ rp2, int* __restrict__ cur2,
                          int* __restrict__ c2s, int E) {
  int e = blockIdx.x * blockDim.x + threadIdx.x;
  if (e >= E) return;
  {
    int d = d1[e];
    int p = atomicAdd(&cur1[d], 1);
    int idx = rp1[d] + p;
    c1s[idx] = s1[e];
    c1v[idx] = v1[e];
  }
  {
    int d = d2[e];
    int p = atomicAdd(&cur2[d], 1);
    c2s[rp2[d] + p] = s2[e];
  }
}

// ---------------- gc1: weighted SPMM + bias + relu + l2norm (wave per node) ----------------

__global__ __launch_bounds__(256) void k_gc1(const int* __restrict__ rp, const int* __restrict__ csrc,
                                             const float* __restrict__ cval, const float* __restrict__ W,
                                             const float* __restrict__ b, float* __restrict__ out, int n) {
  int gw = (blockIdx.x * 256 + threadIdx.x) >> 6;
  int lane = threadIdx.x & 63;
  if (gw >= n) return;
  int s = rp[gw], e = rp[gw + 1];
  float a0 = 0.f, a1 = 0.f;
  for (int i = s; i < e; ++i) {
    int src = csrc[i];
    float v = cval[i];
    const float* wr = W + (size_t)src * NH;
    a0 = fmaf(v, wr[lane], a0);
    if (lane < 32) a1 = fmaf(v, wr[64 + lane], a1);
  }
  a0 = fmaxf(a0 + b[lane], 0.f);
  if (lane < 32) a1 = fmaxf(a1 + b[64 + lane], 0.f); else a1 = 0.f;
  float ss = a0 * a0 + a1 * a1;
#pragma unroll
  for (int o = 1; o < 64; o <<= 1) ss += __shfl_xor(ss, o);
  float sc = 1.f / fmaxf(sqrtf(ss), 1e-12f);
  out[(size_t)gw * NH + lane] = a0 * sc;
  if (lane < 32) out[(size_t)gw * NH + 64 + lane] = a1 * sc;
}

// ---------------- mean aggregation (wave per node) ----------------

__global__ __launch_bounds__(256) void k_agg(const int* __restrict__ rp, const int* __restrict__ csrc,
                                             const float* __restrict__ X, float* __restrict__ out, int n) {
  int gw = (blockIdx.x * 256 + threadIdx.x) >> 6;
  int lane = threadIdx.x & 63;
  if (gw >= n) return;
  int s = rp[gw], e = rp[gw + 1];
  float a0 = 0.f, a1 = 0.f;
  for (int i = s; i < e; ++i) {
    const float* xr = X + (size_t)csrc[i] * NH;
    a0 += xr[lane];
    if (lane < 32) a1 += xr[64 + lane];
  }
  float inv = 1.f / fmaxf((float)(e - s), 1.f);
  out[(size_t)gw * NH + lane] = a0 * inv;
  if (lane < 32) out[(size_t)gw * NH + 64 + lane] = a1 * inv;
}

// ---------------- SAGE GEMM: Y = epi(A@Wl + X@Wr + b) ----------------
// 128 nodes/block, 256 threads: 32 node-groups(4 nodes) x 8 col-groups(12 cols)
// EPI 0: relu + l2norm; EPI 1: relu only

template <int EPI>
__global__ __launch_bounds__(256) void k_sage(const float* __restrict__ A, const float* __restrict__ Wl,
                                              const float* __restrict__ X, const float* __restrict__ Wr,
                                              const float* __restrict__ bias, float* __restrict__ Y, int n) {
  __shared__ float sX[128 * 17];
  __shared__ float sW[16 * NH];
  int tid = threadIdx.x;
  int ng = tid >> 3;   // 0..31
  int cg = tid & 7;    // 0..7
  int base = blockIdx.x * 128;
  float acc[4][12];
#pragma unroll
  for (int m = 0; m < 4; ++m)
#pragma unroll
    for (int j = 0; j < 12; ++j) acc[m][j] = 0.f;

  for (int pass = 0; pass < 2; ++pass) {
    const float* Xp = pass ? X : A;
    const float* Wp = pass ? Wr : Wl;
    for (int k0 = 0; k0 < NH; k0 += 16) {
      __syncthreads();
#pragma unroll
      for (int i = 0; i < 8; ++i) {
        int f = tid + 256 * i;           // < 2048
        int nl = f >> 4, kk = f & 15;
        int row = base + nl;
        sX[nl * 17 + kk] = (row < n) ? Xp[(size_t)row * NH + k0 + kk] : 0.f;
      }
#pragma unroll
      for (int i = 0; i < 6; ++i) {
        int f = tid + 256 * i;           // < 1536
        sW[f] = Wp[k0 * NH + f];
      }
      __syncthreads();
#pragma unroll
      for (int kk = 0; kk < 16; ++kk) {
        float xv[4], wv[12];
#pragma unroll
        for (int m = 0; m < 4; ++m) xv[m] = sX[(ng * 4 + m) * 17 + kk];
#pragma unroll
        for (int j = 0; j < 12; ++j) wv[j] = sW[kk * NH + cg * 12 + j];
#pragma unroll
        for (int m = 0; m < 4; ++m)
#pragma unroll
          for (int j = 0; j < 12; ++j) acc[m][j] = fmaf(xv[m], wv[j], acc[m][j]);
      }
    }
  }

#pragma unroll
  for (int m = 0; m < 4; ++m)
#pragma unroll
    for (int j = 0; j < 12; ++j) acc[m][j] = fmaxf(acc[m][j] + bias[cg * 12 + j], 0.f);

  if (EPI == 0) {
#pragma unroll
    for (int m = 0; m < 4; ++m) {
      float ss = 0.f;
#pragma unroll
      for (int j = 0; j < 12; ++j) ss = fmaf(acc[m][j], acc[m][j], ss);
      ss += __shfl_xor(ss, 1);
      ss += __shfl_xor(ss, 2);
      ss += __shfl_xor(ss, 4);
      float sc = 1.f / fmaxf(sqrtf(ss), 1e-12f);
#pragma unroll
      for (int j = 0; j < 12; ++j) acc[m][j] *= sc;
    }
  }

#pragma unroll
  for (int m = 0; m < 4; ++m) {
    int node = base + ng * 4 + m;
    if (node < n) {
      float4* yo = (float4*)(Y + (size_t)node * NH + cg * 12);
#pragma unroll
      for (int q = 0; q < 3; ++q)
        yo[q] = make_float4(acc[m][4 * q], acc[m][4 * q + 1], acc[m][4 * q + 2], acc[m][4 * q + 3]);
    }
  }
}

// ---------------- MLP layer 1: H = relu(X@W1 + b1), [N,96]->[N,192] ----------------
// 128 nodes/block: 32 node-groups(4) x 8 col-groups(24 cols)

__global__ __launch_bounds__(256) void k_mlp12(const float* __restrict__ X, const float* __restrict__ W1,
                                               const float* __restrict__ b1, float* __restrict__ H, int n) {
  __shared__ float sX[128 * 17];
  __shared__ float sW[16 * NH2];
  int tid = threadIdx.x;
  int ng = tid >> 3;
  int cg = tid & 7;
  int base = blockIdx.x * 128;
  float acc[4][24];
#pragma unroll
  for (int m = 0; m < 4; ++m)
#pragma unroll
    for (int j = 0; j < 24; ++j) acc[m][j] = 0.f;

  for (int k0 = 0; k0 < NH; k0 += 16) {
    __syncthreads();
#pragma unroll
    for (int i = 0; i < 8; ++i) {
      int f = tid + 256 * i;
      int nl = f >> 4, kk = f & 15;
      int row = base + nl;
      sX[nl * 17 + kk] = (row < n) ? X[(size_t)row * NH + k0 + kk] : 0.f;
    }
#pragma unroll
    for (int i = 0; i < 12; ++i) {
      int f = tid + 256 * i;            // < 3072
      sW[f] = W1[k0 * NH2 + f];
    }
    __syncthreads();
#pragma unroll
    for (int kk = 0; kk < 16; ++kk) {
      float xv[4], wv[24];
#pragma unroll
      for (int m = 0; m < 4; ++m) xv[m] = sX[(ng * 4 + m) * 17 + kk];
#pragma unroll
      for (int j = 0; j < 24; ++j) wv[j] = sW[kk * NH2 + cg * 24 + j];
#pragma unroll
      for (int m = 0; m < 4; ++m)
#pragma unroll
        for (int j = 0; j < 24; ++j) acc[m][j] = fmaf(xv[m], wv[j], acc[m][j]);
    }
  }

#pragma unroll
  for (int m = 0; m < 4; ++m) {
    int node = base + ng * 4 + m;
    if (node < n) {
      float4* ho = (float4*)(H + (size_t)node * NH2 + cg * 24);
#pragma unroll
      for (int q = 0; q < 6; ++q) {
        float v0 = fmaxf(acc[m][4 * q + 0] + b1[cg * 24 + 4 * q + 0], 0.f);
        float v1 = fmaxf(acc[m][4 * q + 1] + b1[cg * 24 + 4 * q + 1], 0.f);
        float v2 = fmaxf(acc[m][4 * q + 2] + b1[cg * 24 + 4 * q + 2], 0.f);
        float v3 = fmaxf(acc[m][4 * q + 3] + b1[cg * 24 + 4 * q + 3], 0.f);
        ho[q] = make_float4(v0, v1, v2, v3);
      }
    }
  }
}

// ---------------- MLP layers 2+3 fused: score += relu(H@W2+b2)@W3 + b3 ----------------

__global__ __launch_bounds__(256) void k_mlp23(const float* __restrict__ H, const float* __restrict__ W2,
                                               const float* __restrict__ b2, const float* __restrict__ W3,
                                               const float* __restrict__ b3, float* __restrict__ score, int n) {
  __shared__ float sX[128 * 17];
  __shared__ float sW[16 * NH2];
  int tid = threadIdx.x;
  int ng = tid >> 3;
  int cg = tid & 7;
  int base = blockIdx.x * 128;
  float acc[4][24];
#pragma unroll
  for (int m = 0; m < 4; ++m)
#pragma unroll
    for (int j = 0; j < 24; ++j) acc[m][j] = 0.f;

  for (int k0 = 0; k0 < NH2; k0 += 16) {
    __syncthreads();
#pragma unroll
    for (int i = 0; i < 8; ++i) {
      int f = tid + 256 * i;
      int nl = f >> 4, kk = f & 15;
      int row = base + nl;
      sX[nl * 17 + kk] = (row < n) ? H[(size_t)row * NH2 + k0 + kk] : 0.f;
    }
#pragma unroll
    for (int i = 0; i < 12; ++i) {
      int f = tid + 256 * i;
      sW[f] = W2[k0 * NH2 + f];
    }
    __syncthreads();
#pragma unroll
    for (int kk = 0; kk < 16; ++kk) {
      float xv[4], wv[24];
#pragma unroll
      for (int m = 0; m < 4; ++m) xv[m] = sX[(ng * 4 + m) * 17 + kk];
#pragma unroll
      for (int j = 0; j < 24; ++j) wv[j] = sW[kk * NH2 + cg * 24 + j];
#pragma unroll
      for (int m = 0; m < 4; ++m)
#pragma unroll
        for (int j = 0; j < 24; ++j) acc[m][j] = fmaf(xv[m], wv[j], acc[m][j]);
    }
  }

  float b3v = b3[0];
#pragma unroll
  for (int m = 0; m < 4; ++m) {
    float p = 0.f;
#pragma unroll
    for (int j = 0; j < 24; ++j) {
      float h2 = fmaxf(acc[m][j] + b2[cg * 24 + j], 0.f);
      p = fmaf(h2, W3[cg * 24 + j], p);
    }
    p += __shfl_xor(p, 1);
    p += __shfl_xor(p, 2);
    p += __shfl_xor(p, 4);
    int node = base + ng * 4 + m;
    if (cg == 0 && node < n) score[node] += p + b3v;
  }
}

// ---------------- host ----------------

extern "C" void kernel_launch(void* const* d_in, const int* in_sizes, int n_in,
                              void* d_out, int out_size, void* d_ws, size_t ws_size,
                              hipStream_t stream) {
  const int* ei1 = (const int*)d_in[0];
  const float* ev1 = (const float*)d_in[1];
  const int* ei2 = (const int*)d_in[2];
  const float* gW = (const float*)d_in[3];
  const float* gb = (const float*)d_in[4];
  const float* sWl = (const float*)d_in[5];
  const float* sbl = (const float*)d_in[6];
  const float* sWr = (const float*)d_in[7];
  const float* W1 = (const float*)d_in[8];
  const float* b1 = (const float*)d_in[9];
  const float* W2 = (const float*)d_in[10];
  const float* b2 = (const float*)d_in[11];
  const float* W3 = (const float*)d_in[12];
  const float* b3 = (const float*)d_in[13];
  float* score = (float*)d_out;

  const int E = in_sizes[0] / 2;
  const int n = in_sizes[3] / NH;

  const int* d1 = ei1;      // edge_index1[0] = dst
  const int* s1 = ei1 + E;  // edge_index1[1] = src
  const int* s2 = ei2;      // edge_index2[0] = src
  const int* d2 = ei2 + E;  // edge_index2[1] = dst

  char* w = (char*)d_ws;
  auto alloc = [&](size_t bytes) {
    char* p = w;
    w += (bytes + 255) & ~(size_t)255;
    return p;
  };
  int* cnt1 = (int*)alloc((size_t)n * 4);
  int* cnt2 = (int*)alloc((size_t)n * 4);
  int* cur1 = (int*)alloc((size_t)n * 4);
  int* cur2 = (int*)alloc((size_t)n * 4);
  int* rp1 = (int*)alloc((size_t)(n + 1) * 4);
  int* rp2 = (int*)alloc((size_t)(n + 1) * 4);
  int* c1s = (int*)alloc((size_t)E * 4);
  float* c1v = (float*)alloc((size_t)E * 4);
  int* c2s = (int*)alloc((size_t)E * 4);
  float* x21 = (float*)alloc((size_t)n * NH * 4);
  float* Ag = (float*)alloc((size_t)n * NH * 4);
  float* xb = (float*)alloc((size_t)n * NH * 4);
  float* tb = (float*)alloc((size_t)n * NH * 4);
  float* h1 = (float*)alloc((size_t)n * NH2 * 4);

  // zero: cnt1..cur2 region (contiguous incl. align padding) + score
  size_t zbytes = (size_t)((char*)cur2 - (char*)cnt1) + (size_t)n * 4;
  hipMemsetAsync(cnt1, 0, zbytes, stream);
  hipMemsetAsync(score, 0, (size_t)n * 4, stream);

  int eb = (E + 255) / 256;
  int nb4 = (n + 3) / 4;        // wave-per-node kernels
  int gb128 = (n + 127) / 128;  // 128-node GEMM blocks

  k_count<<<eb, 256, 0, stream>>>(d1, d2, cnt1, cnt2, E);
  k_scan<<<1, 1024, 0, stream>>>(cnt1, rp1, n);
  k_scan<<<1, 1024, 0, stream>>>(cnt2, rp2, n);
  k_scatter<<<eb, 256, 0, stream>>>(d1, s1, ev1, rp1, cur1, c1s, c1v, s2, d2, rp2, cur2, c2s, E);

  // x2_1 = l2norm(relu(spmm(adj1, gc1_W) + gc1_b))
  k_gc1<<<nb4, 256, 0, stream>>>(rp1, c1s, c1v, gW, gb, x21, n);

  auto mlp = [&](const float* Xf) {
    k_mlp12<<<gb128, 256, 0, stream>>>(Xf, W1, b1, h1, n);
    k_mlp23<<<gb128, 256, 0, stream>>>(h1, W2, b2, W3, b3, score, n);
  };

  // score += mlp(x2_1)
  mlp(x21);

  // A2 = mean-agg(x2_1) over edge_index2 — reused by trunk layer 0 AND all 6 score branches
  k_agg<<<nb4, 256, 0, stream>>>(rp2, c2s, x21, Ag, n);

  // trunk layer 0 (== score branch i=0)
  k_sage<0><<<gb128, 256, 0, stream>>>(Ag, sWl, x21, sWr, sbl, xb, n);
  mlp(xb);

  // score branches i=1..5 (all use A2 and x2_1)
  for (int i = 1; i < 6; ++i) {
    k_sage<0><<<gb128, 256, 0, stream>>>(Ag, sWl + (size_t)i * NH * NH, x21,
                                         sWr + (size_t)i * NH * NH, sbl + (size_t)i * NH, tb, n);
    mlp(tb);
  }

  // trunk layers 1..5
  float* xc = xb;
  float* xn = tb;
  for (int i = 1; i < 6; ++i) {
    k_agg<<<nb4, 256, 0, stream>>>(rp2, c2s, xc, Ag, n);
    k_sage<0><<<gb128, 256, 0, stream>>>(Ag, sWl + (size_t)i * NH * NH, xc,
                                         sWr + (size_t)i * NH * NH, sbl + (size_t)i * NH, xn, n);
    float* tmp = xc; xc = xn; xn = tmp;
  }

  // last layer: relu only, then final mlp
  k_agg<<<nb4, 256, 0, stream>>>(rp2, c2s, xc, Ag, n);
  k_sage<1><<<gb128, 256, 0, stream>>>(Ag, sWl + (size_t)6 * NH * NH, xc,
                                       sWr + (size_t)6 * NH * NH, sbl + (size_t)6 * NH, xn, n);
  mlp(xn);

  (void)n_in; (void)out_size; (void)ws_size;
}

// Round 2
// 1655.008 us; speedup vs baseline: 1.5630x; 1.5630x over previous
//
#include <hip/hip_runtime.h>

#define NH 96
#define NH2 192

typedef __attribute__((ext_vector_type(8))) short short8;
typedef __attribute__((ext_vector_type(4))) float f32x4;

__device__ __forceinline__ unsigned short f2b(float f) {
  unsigned u = __float_as_uint(f);
  unsigned r = (u + 0x7FFFu + ((u >> 16) & 1u)) >> 16;
  return (unsigned short)r;
}

// ---------------- CSR build ----------------

__global__ void k_count(const int* __restrict__ dst1, const int* __restrict__ dst2,
                        int* __restrict__ cnt1, int* __restrict__ cnt2, int E) {
  int e = blockIdx.x * blockDim.x + threadIdx.x;
  if (e < E) {
    atomicAdd(&cnt1[dst1[e]], 1);
    atomicAdd(&cnt2[dst2[e]], 1);
  }
}

__global__ __launch_bounds__(1024) void k_scan(const int* __restrict__ cnt, int* __restrict__ rp, int n) {
  __shared__ int s[1024];
  int tid = threadIdx.x;
  int chunk = (n + 1023) >> 10;
  int beg = tid * chunk;
  int end = min(beg + chunk, n);
  int sum = 0;
  for (int i = beg; i < end; ++i) sum += cnt[i];
  s[tid] = sum;
  __syncthreads();
  for (int off = 1; off < 1024; off <<= 1) {
    int v = (tid >= off) ? s[tid - off] : 0;
    __syncthreads();
    s[tid] += v;
    __syncthreads();
  }
  int excl = (tid == 0) ? 0 : s[tid - 1];
  for (int i = beg; i < end; ++i) { rp[i] = excl; excl += cnt[i]; }
  if (tid == 1023) rp[n] = s[1023];
}

__global__ void k_scatter(const int* __restrict__ d1, const int* __restrict__ s1, const float* __restrict__ v1,
                          const int* __restrict__ rp1, int* __restrict__ cur1,
                          int* __restrict__ c1s, float* __restrict__ c1v,
                          const int* __restrict__ s2, const int* __restrict__ d2,
                          const int* __restrict__ rp2, int* __restrict__ cur2,
                          int* __restrict__ c2s, int E) {
  int e = blockIdx.x * blockDim.x + threadIdx.x;
  if (e >= E) return;
  {
    int d = d1[e];
    int p = atomicAdd(&cur1[d], 1);
    int idx = rp1[d] + p;
    c1s[idx] = s1[e];
    c1v[idx] = v1[e];
  }
  {
    int d = d2[e];
    int p = atomicAdd(&cur2[d], 1);
    c2s[rp2[d] + p] = s2[e];
  }
}

// ---------------- weight prep: fp32 -> bf16 (+ transpose for GEMM B-operands) ----------------

__global__ void k_cvtgw(const float* __restrict__ W, unsigned short* __restrict__ Wb, int total) {
  int i = (blockIdx.x * blockDim.x + threadIdx.x) * 4;
  if (i + 3 < total) {
    float4 v = *(const float4*)(W + i);
    ushort4 o;
    o.x = f2b(v.x); o.y = f2b(v.y); o.z = f2b(v.z); o.w = f2b(v.w);
    *(ushort4*)(Wb + i) = o;
  }
}

// pack Wl/Wr (7x96x96), W1 (96x192), W2 (192x192) into transposed [N][K] bf16
__global__ void k_packw(const float* __restrict__ Wl, const float* __restrict__ Wr,
                        const float* __restrict__ W1, const float* __restrict__ W2,
                        unsigned short* __restrict__ WlT, unsigned short* __restrict__ WrT,
                        unsigned short* __restrict__ W1T, unsigned short* __restrict__ W2T) {
  int t = blockIdx.x * blockDim.x + threadIdx.x;
  if (t < 64512) {                       // 7*9216 Wl
    int i = t / 9216, r = t % 9216, nn = r / 96, k = r % 96;
    WlT[t] = f2b(Wl[i * 9216 + k * 96 + nn]);
  } else if (t < 129024) {               // Wr
    int u = t - 64512;
    int i = u / 9216, r = u % 9216, nn = r / 96, k = r % 96;
    WrT[u] = f2b(Wr[i * 9216 + k * 96 + nn]);
  } else if (t < 147456) {               // W1 [96][192] -> [192][96]
    int u = t - 129024, nn = u / 96, k = u % 96;
    W1T[u] = f2b(W1[k * 192 + nn]);
  } else if (t < 184320) {               // W2 [192][192] -> [192][192]T
    int u = t - 147456, nn = u / 192, k = u % 192;
    W2T[u] = f2b(W2[k * 192 + nn]);
  }
}

// ---------------- gc1: weighted SPMM (bf16 W gather) + bias + relu + l2norm ----------------

__global__ __launch_bounds__(256) void k_gc1(const int* __restrict__ rp, const int* __restrict__ csrc,
                                             const float* __restrict__ cval, const unsigned short* __restrict__ Wb,
                                             const float* __restrict__ b, unsigned short* __restrict__ out, int n) {
  int gw = (blockIdx.x * 256 + threadIdx.x) >> 6;
  int l = threadIdx.x & 63;
  if (gw >= n) return;
  int s = rp[gw], e = rp[gw + 1];
  bool act = l < 48;
  float a0 = 0.f, a1 = 0.f;
  for (int i = s; i < e; ++i) {
    int src = csrc[i];
    float v = cval[i];
    if (act) {
      unsigned w = *(const unsigned*)(Wb + (size_t)src * NH + 2 * l);
      a0 = fmaf(v, __uint_as_float(w << 16), a0);
      a1 = fmaf(v, __uint_as_float(w & 0xFFFF0000u), a1);
    }
  }
  if (act) {
    a0 = fmaxf(a0 + b[2 * l], 0.f);
    a1 = fmaxf(a1 + b[2 * l + 1], 0.f);
  } else { a0 = a1 = 0.f; }
  float ss = a0 * a0 + a1 * a1;
#pragma unroll
  for (int o = 1; o < 64; o <<= 1) ss += __shfl_xor(ss, o);
  float sc = 1.f / fmaxf(sqrtf(ss), 1e-12f);
  if (act) {
    unsigned pk = ((unsigned)f2b(a1 * sc) << 16) | f2b(a0 * sc);
    ((unsigned*)out)[(size_t)gw * 48 + l] = pk;
  }
}

// ---------------- mean aggregation over bf16 rows ----------------

__global__ __launch_bounds__(256) void k_agg(const int* __restrict__ rp, const int* __restrict__ csrc,
                                             const unsigned short* __restrict__ X,
                                             unsigned short* __restrict__ out, int n) {
  int gw = (blockIdx.x * 256 + threadIdx.x) >> 6;
  int l = threadIdx.x & 63;
  if (gw >= n) return;
  int s = rp[gw], e = rp[gw + 1];
  bool act = l < 48;
  float a0 = 0.f, a1 = 0.f;
  for (int i = s; i < e; ++i) {
    int src = csrc[i];
    if (act) {
      unsigned w = *(const unsigned*)(X + (size_t)src * NH + 2 * l);
      a0 += __uint_as_float(w << 16);
      a1 += __uint_as_float(w & 0xFFFF0000u);
    }
  }
  float inv = 1.f / fmaxf((float)(e - s), 1.f);
  if (act) {
    unsigned pk = ((unsigned)f2b(a1 * inv) << 16) | f2b(a0 * inv);
    ((unsigned*)out)[(size_t)gw * 48 + l] = pk;
  }
}

// ---------------- SAGE MFMA GEMM: Y = epi(A@Wl + X@Wr + b), [n,96] ----------------
// wave per 16 rows; 6 N-tiles of 16; K=96 per pass; EPI 0: relu+l2norm, 1: relu

template <int EPI>
__global__ __launch_bounds__(256) void k_sage(const unsigned short* __restrict__ A, const unsigned short* __restrict__ WlT,
                                              const unsigned short* __restrict__ X, const unsigned short* __restrict__ WrT,
                                              const float* __restrict__ bias, unsigned short* __restrict__ Y, int n) {
  int wv = blockIdx.x * 4 + (threadIdx.x >> 6);
  int l = threadIdx.x & 63;
  int m0 = wv * 16;
  if (m0 >= n) return;
  int c = l & 15, g = l >> 4;
  int arow = min(m0 + c, n - 1);
  size_t aoff = (size_t)arow * NH + g * 8;

  f32x4 acc[6];
#pragma unroll
  for (int t = 0; t < 6; ++t) acc[t] = (f32x4){0.f, 0.f, 0.f, 0.f};

  const unsigned short* Ap[2] = {A, X};
  const unsigned short* Wp[2] = {WlT, WrT};
#pragma unroll
  for (int p = 0; p < 2; ++p) {
#pragma unroll
    for (int k0 = 0; k0 < NH; k0 += 32) {
      short8 af = *(const short8*)(Ap[p] + aoff + k0);
#pragma unroll
      for (int t = 0; t < 6; ++t) {
        short8 bfr = *(const short8*)(Wp[p] + (size_t)(t * 16 + c) * NH + k0 + g * 8);
        acc[t] = __builtin_amdgcn_mfma_f32_16x16x32_bf16(af, bfr, acc[t], 0, 0, 0);
      }
    }
  }

  float v[6][4];
#pragma unroll
  for (int t = 0; t < 6; ++t) {
    float bv = bias[t * 16 + c];
#pragma unroll
    for (int r = 0; r < 4; ++r) v[t][r] = fmaxf(acc[t][r] + bv, 0.f);
  }

  if (EPI == 0) {
#pragma unroll
    for (int r = 0; r < 4; ++r) {
      float ss = 0.f;
#pragma unroll
      for (int t = 0; t < 6; ++t) ss = fmaf(v[t][r], v[t][r], ss);
      ss += __shfl_xor(ss, 1);
      ss += __shfl_xor(ss, 2);
      ss += __shfl_xor(ss, 4);
      ss += __shfl_xor(ss, 8);
      float sc = 1.f / fmaxf(sqrtf(ss), 1e-12f);
#pragma unroll
      for (int t = 0; t < 6; ++t) v[t][r] *= sc;
    }
  }

#pragma unroll
  for (int r = 0; r < 4; ++r) {
    int row = m0 + g * 4 + r;
    if (row < n) {
#pragma unroll
      for (int t = 0; t < 6; ++t) Y[(size_t)row * NH + t * 16 + c] = f2b(v[t][r]);
    }
  }
}

// ---------------- MLP layer 1 MFMA: H = relu(X@W1 + b1), [n,96]->[n,192] ----------------

__global__ __launch_bounds__(256) void k_mlp12(const unsigned short* __restrict__ X, const unsigned short* __restrict__ W1T,
                                               const float* __restrict__ b1, unsigned short* __restrict__ H, int n) {
  int wv = blockIdx.x * 4 + (threadIdx.x >> 6);
  int l = threadIdx.x & 63;
  int m0 = wv * 16;
  if (m0 >= n) return;
  int c = l & 15, g = l >> 6 ? 0 : l >> 4;  // g = l>>4
  g = l >> 4;
  int arow = min(m0 + c, n - 1);
  size_t aoff = (size_t)arow * NH + g * 8;

  f32x4 acc[12];
#pragma unroll
  for (int t = 0; t < 12; ++t) acc[t] = (f32x4){0.f, 0.f, 0.f, 0.f};

#pragma unroll
  for (int k0 = 0; k0 < NH; k0 += 32) {
    short8 af = *(const short8*)(X + aoff + k0);
#pragma unroll
    for (int t = 0; t < 12; ++t) {
      short8 bfr = *(const short8*)(W1T + (size_t)(t * 16 + c) * NH + k0 + g * 8);
      acc[t] = __builtin_amdgcn_mfma_f32_16x16x32_bf16(af, bfr, acc[t], 0, 0, 0);
    }
  }

#pragma unroll
  for (int r = 0; r < 4; ++r) {
    int row = m0 + g * 4 + r;
    if (row < n) {
#pragma unroll
      for (int t = 0; t < 12; ++t) {
        float vv = fmaxf(acc[t][r] + b1[t * 16 + c], 0.f);
        H[(size_t)row * NH2 + t * 16 + c] = f2b(vv);
      }
    }
  }
}

// ---------------- MLP layers 2+3 MFMA fused: score += relu(H@W2+b2)@W3 + b3 ----------------

__global__ __launch_bounds__(256) void k_mlp23(const unsigned short* __restrict__ H, const unsigned short* __restrict__ W2T,
                                               const float* __restrict__ b2, const float* __restrict__ W3,
                                               const float* __restrict__ b3, float* __restrict__ score, int n) {
  int wv = blockIdx.x * 4 + (threadIdx.x >> 6);
  int l = threadIdx.x & 63;
  int m0 = wv * 16;
  if (m0 >= n) return;
  int c = l & 15, g = l >> 4;
  int arow = min(m0 + c, n - 1);
  size_t aoff = (size_t)arow * NH2 + g * 8;

  f32x4 acc[12];
#pragma unroll
  for (int t = 0; t < 12; ++t) acc[t] = (f32x4){0.f, 0.f, 0.f, 0.f};

#pragma unroll
  for (int k0 = 0; k0 < NH2; k0 += 32) {
    short8 af = *(const short8*)(H + aoff + k0);
#pragma unroll
    for (int t = 0; t < 12; ++t) {
      short8 bfr = *(const short8*)(W2T + (size_t)(t * 16 + c) * NH2 + k0 + g * 8);
      acc[t] = __builtin_amdgcn_mfma_f32_16x16x32_bf16(af, bfr, acc[t], 0, 0, 0);
    }
  }

  float b3v = b3[0];
#pragma unroll
  for (int r = 0; r < 4; ++r) {
    float s = 0.f;
#pragma unroll
    for (int t = 0; t < 12; ++t) {
      float h2 = fmaxf(acc[t][r] + b2[t * 16 + c], 0.f);
      s = fmaf(h2, W3[t * 16 + c], s);
    }
    s += __shfl_xor(s, 1);
    s += __shfl_xor(s, 2);
    s += __shfl_xor(s, 4);
    s += __shfl_xor(s, 8);
    int row = m0 + g * 4 + r;
    if (c == 0 && row < n) score[row] += s + b3v;
  }
}

// ---------------- host ----------------

extern "C" void kernel_launch(void* const* d_in, const int* in_sizes, int n_in,
                              void* d_out, int out_size, void* d_ws, size_t ws_size,
                              hipStream_t stream) {
  const int* ei1 = (const int*)d_in[0];
  const float* ev1 = (const float*)d_in[1];
  const int* ei2 = (const int*)d_in[2];
  const float* gW = (const float*)d_in[3];
  const float* gb = (const float*)d_in[4];
  const float* sWl = (const float*)d_in[5];
  const float* sbl = (const float*)d_in[6];
  const float* sWr = (const float*)d_in[7];
  const float* W1 = (const float*)d_in[8];
  const float* b1 = (const float*)d_in[9];
  const float* W2 = (const float*)d_in[10];
  const float* b2 = (const float*)d_in[11];
  const float* W3 = (const float*)d_in[12];
  const float* b3 = (const float*)d_in[13];
  float* score = (float*)d_out;

  const int E = in_sizes[0] / 2;
  const int n = in_sizes[3] / NH;

  const int* d1 = ei1;      // edge_index1[0] = dst
  const int* s1 = ei1 + E;  // edge_index1[1] = src
  const int* s2 = ei2;      // edge_index2[0] = src
  const int* d2 = ei2 + E;  // edge_index2[1] = dst

  char* w = (char*)d_ws;
  auto alloc = [&](size_t bytes) {
    char* p = w;
    w += (bytes + 255) & ~(size_t)255;
    return p;
  };
  int* cnt1 = (int*)alloc((size_t)n * 4);
  int* cnt2 = (int*)alloc((size_t)n * 4);
  int* cur1 = (int*)alloc((size_t)n * 4);
  int* cur2 = (int*)alloc((size_t)n * 4);
  int* rp1 = (int*)alloc((size_t)(n + 1) * 4);
  int* rp2 = (int*)alloc((size_t)(n + 1) * 4);
  int* c1s = (int*)alloc((size_t)E * 4);
  float* c1v = (float*)alloc((size_t)E * 4);
  int* c2s = (int*)alloc((size_t)E * 4);
  unsigned short* gwb = (unsigned short*)alloc((size_t)n * NH * 2);
  unsigned short* wlt = (unsigned short*)alloc((size_t)7 * NH * NH * 2);
  unsigned short* wrt = (unsigned short*)alloc((size_t)7 * NH * NH * 2);
  unsigned short* w1t = (unsigned short*)alloc((size_t)NH * NH2 * 2);
  unsigned short* w2t = (unsigned short*)alloc((size_t)NH2 * NH2 * 2);
  unsigned short* x21 = (unsigned short*)alloc((size_t)n * NH * 2);
  unsigned short* Ag = (unsigned short*)alloc((size_t)n * NH * 2);
  unsigned short* xb = (unsigned short*)alloc((size_t)n * NH * 2);
  unsigned short* tb = (unsigned short*)alloc((size_t)n * NH * 2);
  unsigned short* h1 = (unsigned short*)alloc((size_t)n * NH2 * 2);

  size_t zbytes = (size_t)((char*)cur2 - (char*)cnt1) + (size_t)n * 4;
  hipMemsetAsync(cnt1, 0, zbytes, stream);
  hipMemsetAsync(score, 0, (size_t)n * 4, stream);

  int eb = (E + 255) / 256;
  int nb4 = (n + 3) / 4;                       // wave-per-node kernels
  int gwav = (n + 15) / 16;                    // MFMA waves
  int gblk = (gwav + 3) / 4;                   // 4 waves/block

  k_count<<<eb, 256, 0, stream>>>(d1, d2, cnt1, cnt2, E);
  k_scan<<<1, 1024, 0, stream>>>(cnt1, rp1, n);
  k_scan<<<1, 1024, 0, stream>>>(cnt2, rp2, n);
  k_scatter<<<eb, 256, 0, stream>>>(d1, s1, ev1, rp1, cur1, c1s, c1v, s2, d2, rp2, cur2, c2s, E);

  k_cvtgw<<<(n * NH / 4 + 255) / 256, 256, 0, stream>>>(gW, gwb, n * NH);
  k_packw<<<720, 256, 0, stream>>>(sWl, sWr, W1, W2, wlt, wrt, w1t, w2t);

  // x2_1 = l2norm(relu(spmm(adj1, gc1_W) + gc1_b))
  k_gc1<<<nb4, 256, 0, stream>>>(rp1, c1s, c1v, gwb, gb, x21, n);

  auto mlp = [&](const unsigned short* Xf) {
    k_mlp12<<<gblk, 256, 0, stream>>>(Xf, w1t, b1, h1, n);
    k_mlp23<<<gblk, 256, 0, stream>>>(h1, w2t, b2, W3, b3, score, n);
  };

  // score += mlp(x2_1)
  mlp(x21);

  // A2 = mean-agg(x2_1) — reused by trunk layer 0 AND all 6 score branches
  k_agg<<<nb4, 256, 0, stream>>>(rp2, c2s, x21, Ag, n);

  // trunk layer 0 (== score branch i=0)
  k_sage<0><<<gblk, 256, 0, stream>>>(Ag, wlt, x21, wrt, sbl, xb, n);
  mlp(xb);

  // score branches i=1..5 (all use Ag and x2_1)
  for (int i = 1; i < 6; ++i) {
    k_sage<0><<<gblk, 256, 0, stream>>>(Ag, wlt + (size_t)i * NH * NH, x21,
                                        wrt + (size_t)i * NH * NH, sbl + (size_t)i * NH, tb, n);
    mlp(tb);
  }

  // trunk layers 1..5
  unsigned short* xc = xb;
  unsigned short* xn = tb;
  for (int i = 1; i < 6; ++i) {
    k_agg<<<nb4, 256, 0, stream>>>(rp2, c2s, xc, Ag, n);
    k_sage<0><<<gblk, 256, 0, stream>>>(Ag, wlt + (size_t)i * NH * NH, xc,
                                        wrt + (size_t)i * NH * NH, sbl + (size_t)i * NH, xn, n);
    unsigned short* tmp = xc; xc = xn; xn = tmp;
  }

  // last layer: relu only, then final mlp
  k_agg<<<nb4, 256, 0, stream>>>(rp2, c2s, xc, Ag, n);
  k_sage<1><<<gblk, 256, 0, stream>>>(Ag, wlt + (size_t)6 * NH * NH, xc,
                                      wrt + (size_t)6 * NH * NH, sbl + (size_t)6 * NH, xn, n);
  mlp(xn);

  (void)n_in; (void)out_size; (void)ws_size;
}

// Round 3
// 1415.100 us; speedup vs baseline: 1.8279x; 1.1695x over previous
//
#include <hip/hip_runtime.h>

#define NH 96
#define NH2 192

typedef __attribute__((ext_vector_type(8))) short short8;
typedef __attribute__((ext_vector_type(4))) float f32x4;

__device__ __forceinline__ unsigned short f2b(float f) {
  unsigned u = __float_as_uint(f);
  unsigned r = (u + 0x7FFFu + ((u >> 16) & 1u)) >> 16;
  return (unsigned short)r;
}
__device__ __forceinline__ float blo(unsigned w) { return __uint_as_float(w << 16); }
__device__ __forceinline__ float bhi(unsigned w) { return __uint_as_float(w & 0xFFFF0000u); }

// ---------------- CSR build ----------------

__global__ void k_count(const int* __restrict__ dst1, const int* __restrict__ dst2,
                        int* __restrict__ cnt1, int* __restrict__ cnt2, int E) {
  int e = blockIdx.x * blockDim.x + threadIdx.x;
  if (e < E) {
    atomicAdd(&cnt1[dst1[e]], 1);
    atomicAdd(&cnt2[dst2[e]], 1);
  }
}

__global__ __launch_bounds__(1024) void k_scan(const int* __restrict__ cnt, int* __restrict__ rp, int n) {
  __shared__ int s[1024];
  int tid = threadIdx.x;
  int chunk = (n + 1023) >> 10;
  int beg = tid * chunk;
  int end = min(beg + chunk, n);
  int sum = 0;
  for (int i = beg; i < end; ++i) sum += cnt[i];
  s[tid] = sum;
  __syncthreads();
  for (int off = 1; off < 1024; off <<= 1) {
    int v = (tid >= off) ? s[tid - off] : 0;
    __syncthreads();
    s[tid] += v;
    __syncthreads();
  }
  int excl = (tid == 0) ? 0 : s[tid - 1];
  for (int i = beg; i < end; ++i) { rp[i] = excl; excl += cnt[i]; }
  if (tid == 1023) rp[n] = s[1023];
}

__global__ void k_scatter(const int* __restrict__ d1, const int* __restrict__ s1, const float* __restrict__ v1,
                          const int* __restrict__ rp1, int* __restrict__ cur1, int2* __restrict__ c1sv,
                          const int* __restrict__ s2, const int* __restrict__ d2,
                          const int* __restrict__ rp2, int* __restrict__ cur2,
                          int* __restrict__ c2s, int E) {
  int e = blockIdx.x * blockDim.x + threadIdx.x;
  if (e >= E) return;
  {
    int d = d1[e];
    int p = atomicAdd(&cur1[d], 1);
    c1sv[rp1[d] + p] = make_int2(s1[e], __float_as_int(v1[e]));
  }
  {
    int d = d2[e];
    int p = atomicAdd(&cur2[d], 1);
    c2s[rp2[d] + p] = s2[e];
  }
}

// ---------------- weight prep ----------------

__global__ void k_cvtgw(const float* __restrict__ W, unsigned short* __restrict__ Wb, int total) {
  int i = (blockIdx.x * blockDim.x + threadIdx.x) * 4;
  if (i + 3 < total) {
    float4 v = *(const float4*)(W + i);
    ushort4 o;
    o.x = f2b(v.x); o.y = f2b(v.y); o.z = f2b(v.z); o.w = f2b(v.w);
    *(ushort4*)(Wb + i) = o;
  }
}

// pack Wl/Wr (7x96x96), W1 (96x192), W2 (192x192) into transposed [N][K] bf16
__global__ void k_packw(const float* __restrict__ Wl, const float* __restrict__ Wr,
                        const float* __restrict__ W1, const float* __restrict__ W2,
                        unsigned short* __restrict__ WlT, unsigned short* __restrict__ WrT,
                        unsigned short* __restrict__ W1T, unsigned short* __restrict__ W2T) {
  int t = blockIdx.x * blockDim.x + threadIdx.x;
  if (t < 64512) {
    int i = t / 9216, r = t % 9216, nn = r / 96, k = r % 96;
    WlT[t] = f2b(Wl[i * 9216 + k * 96 + nn]);
  } else if (t < 129024) {
    int u = t - 64512;
    int i = u / 9216, r = u % 9216, nn = r / 96, k = r % 96;
    WrT[u] = f2b(Wr[i * 9216 + k * 96 + nn]);
  } else if (t < 147456) {
    int u = t - 129024, nn = u / 96, k = u % 96;
    W1T[u] = f2b(W1[k * 192 + nn]);
  } else if (t < 184320) {
    int u = t - 147456, nn = u / 192, k = u % 192;
    W2T[u] = f2b(W2[k * 192 + nn]);
  }
}

// ---------------- gc1: weighted SPMM + bias + relu + l2norm ----------------

__global__ __launch_bounds__(256) void k_gc1(const int* __restrict__ rp, const int2* __restrict__ cv,
                                             const unsigned short* __restrict__ Wb,
                                             const float* __restrict__ b, unsigned short* __restrict__ out, int n) {
  int gw = (blockIdx.x * 256 + threadIdx.x) >> 6;
  int l = threadIdx.x & 63;
  if (gw >= n) return;
  int s = rp[gw], e = rp[gw + 1];
  bool act = l < 48;
  float a0 = 0.f, a1 = 0.f, c0 = 0.f, c1 = 0.f;
  int i = s;
  for (; i + 1 < e; i += 2) {
    int2 q0 = cv[i], q1 = cv[i + 1];
    if (act) {
      unsigned w0 = *(const unsigned*)(Wb + (size_t)q0.x * NH + 2 * l);
      unsigned w1 = *(const unsigned*)(Wb + (size_t)q1.x * NH + 2 * l);
      float v0 = __int_as_float(q0.y), v1 = __int_as_float(q1.y);
      a0 = fmaf(v0, blo(w0), a0); a1 = fmaf(v0, bhi(w0), a1);
      c0 = fmaf(v1, blo(w1), c0); c1 = fmaf(v1, bhi(w1), c1);
    }
  }
  if (i < e) {
    int2 q0 = cv[i];
    if (act) {
      unsigned w0 = *(const unsigned*)(Wb + (size_t)q0.x * NH + 2 * l);
      float v0 = __int_as_float(q0.y);
      a0 = fmaf(v0, blo(w0), a0); a1 = fmaf(v0, bhi(w0), a1);
    }
  }
  a0 += c0; a1 += c1;
  if (act) {
    a0 = fmaxf(a0 + b[2 * l], 0.f);
    a1 = fmaxf(a1 + b[2 * l + 1], 0.f);
  } else { a0 = a1 = 0.f; }
  float ss = a0 * a0 + a1 * a1;
#pragma unroll
  for (int o = 1; o < 64; o <<= 1) ss += __shfl_xor(ss, o);
  float sc = 1.f / fmaxf(sqrtf(ss), 1e-12f);
  if (act) {
    unsigned pk = ((unsigned)f2b(a1 * sc) << 16) | f2b(a0 * sc);
    ((unsigned*)out)[(size_t)gw * 48 + l] = pk;
  }
}

// ---------------- mean aggregation ----------------

__global__ __launch_bounds__(256) void k_agg(const int* __restrict__ rp, const int* __restrict__ csrc,
                                             const unsigned short* __restrict__ X,
                                             unsigned short* __restrict__ out, int n) {
  int gw = (blockIdx.x * 256 + threadIdx.x) >> 6;
  int l = threadIdx.x & 63;
  if (gw >= n) return;
  int s = rp[gw], e = rp[gw + 1];
  bool act = l < 48;
  float a0 = 0.f, a1 = 0.f, c0 = 0.f, c1 = 0.f;
  int i = s;
  for (; i + 1 < e; i += 2) {
    int s0 = csrc[i], s1 = csrc[i + 1];
    if (act) {
      unsigned w0 = *(const unsigned*)(X + (size_t)s0 * NH + 2 * l);
      unsigned w1 = *(const unsigned*)(X + (size_t)s1 * NH + 2 * l);
      a0 += blo(w0); a1 += bhi(w0);
      c0 += blo(w1); c1 += bhi(w1);
    }
  }
  if (i < e) {
    int s0 = csrc[i];
    if (act) {
      unsigned w0 = *(const unsigned*)(X + (size_t)s0 * NH + 2 * l);
      a0 += blo(w0); a1 += bhi(w0);
    }
  }
  a0 += c0; a1 += c1;
  float inv = 1.f / fmaxf((float)(e - s), 1.f);
  if (act) {
    unsigned pk = ((unsigned)f2b(a1 * inv) << 16) | f2b(a0 * inv);
    ((unsigned*)out)[(size_t)gw * 48 + l] = pk;
  }
}

// ---------------- trunk SAGE MFMA GEMM: Y = epi(A@Wl + X@Wr + b) ----------------

template <int EPI>
__global__ __launch_bounds__(256) void k_sage(const unsigned short* __restrict__ A, const unsigned short* __restrict__ WlT,
                                              const unsigned short* __restrict__ X, const unsigned short* __restrict__ WrT,
                                              const float* __restrict__ bias, unsigned short* __restrict__ Y, int n) {
  int wv = blockIdx.x * 4 + (threadIdx.x >> 6);
  int l = threadIdx.x & 63;
  int m0 = wv * 16;
  if (m0 >= n) return;
  int c = l & 15, g = l >> 4;
  int arow = min(m0 + c, n - 1);
  size_t aoff = (size_t)arow * NH + g * 8;

  f32x4 acc[6];
#pragma unroll
  for (int t = 0; t < 6; ++t) acc[t] = (f32x4){0.f, 0.f, 0.f, 0.f};

#pragma unroll
  for (int k = 0; k < 3; ++k) {
    short8 af = *(const short8*)(A + aoff + k * 32);
#pragma unroll
    for (int t = 0; t < 6; ++t) {
      short8 bfr = *(const short8*)(WlT + (size_t)(t * 16 + c) * NH + k * 32 + g * 8);
      acc[t] = __builtin_amdgcn_mfma_f32_16x16x32_bf16(af, bfr, acc[t], 0, 0, 0);
    }
    short8 xf = *(const short8*)(X + aoff + k * 32);
#pragma unroll
    for (int t = 0; t < 6; ++t) {
      short8 bfr = *(const short8*)(WrT + (size_t)(t * 16 + c) * NH + k * 32 + g * 8);
      acc[t] = __builtin_amdgcn_mfma_f32_16x16x32_bf16(xf, bfr, acc[t], 0, 0, 0);
    }
  }

  float v[6][4];
#pragma unroll
  for (int t = 0; t < 6; ++t) {
    float bv = bias[t * 16 + c];
#pragma unroll
    for (int r = 0; r < 4; ++r) v[t][r] = fmaxf(acc[t][r] + bv, 0.f);
  }

  if (EPI == 0) {
#pragma unroll
    for (int r = 0; r < 4; ++r) {
      float ss = 0.f;
#pragma unroll
      for (int t = 0; t < 6; ++t) ss = fmaf(v[t][r], v[t][r], ss);
      ss += __shfl_xor(ss, 1);
      ss += __shfl_xor(ss, 2);
      ss += __shfl_xor(ss, 4);
      ss += __shfl_xor(ss, 8);
      float sc = 1.f / fmaxf(sqrtf(ss), 1e-12f);
#pragma unroll
      for (int t = 0; t < 6; ++t) v[t][r] *= sc;
    }
  }

#pragma unroll
  for (int r = 0; r < 4; ++r) {
    int row = m0 + g * 4 + r;
    if (row < n) {
#pragma unroll
      for (int t = 0; t < 6; ++t) Y[(size_t)row * NH + t * 16 + c] = f2b(v[t][r]);
    }
  }
}

// ---------------- fused 3-layer MLP: score += mlp(X) ----------------
// wave per 16 rows; H transposed through per-wave LDS tile (stride 200 shorts)

__global__ __launch_bounds__(256) void k_mlp(const unsigned short* __restrict__ X,
                                             const unsigned short* __restrict__ W1T, const float* __restrict__ b1,
                                             const unsigned short* __restrict__ W2T, const float* __restrict__ b2,
                                             const float* __restrict__ W3, const float* __restrict__ b3,
                                             float* __restrict__ score, int n) {
  __shared__ __align__(16) unsigned short sH[4][16 * 200];
  int wid = threadIdx.x >> 6, l = threadIdx.x & 63;
  int m0 = (blockIdx.x * 4 + wid) * 16;
  int c = l & 15, g = l >> 4;
  bool wact = m0 < n;
  int arow = wact ? min(m0 + c, n - 1) : 0;
  unsigned short* hb = sH[wid];

  f32x4 acc1[12];
#pragma unroll
  for (int t = 0; t < 12; ++t) acc1[t] = (f32x4){0.f, 0.f, 0.f, 0.f};
#pragma unroll
  for (int k = 0; k < 3; ++k) {
    short8 af = *(const short8*)(X + (size_t)arow * NH + k * 32 + g * 8);
#pragma unroll
    for (int t = 0; t < 12; ++t) {
      short8 bfr = *(const short8*)(W1T + (size_t)(t * 16 + c) * NH + k * 32 + g * 8);
      acc1[t] = __builtin_amdgcn_mfma_f32_16x16x32_bf16(af, bfr, acc1[t], 0, 0, 0);
    }
  }
#pragma unroll
  for (int t = 0; t < 12; ++t)
#pragma unroll
    for (int r = 0; r < 4; ++r)
      hb[(g * 4 + r) * 200 + t * 16 + c] = f2b(fmaxf(acc1[t][r] + b1[t * 16 + c], 0.f));
  __syncthreads();

  f32x4 acc2[12];
#pragma unroll
  for (int t = 0; t < 12; ++t) acc2[t] = (f32x4){0.f, 0.f, 0.f, 0.f};
#pragma unroll
  for (int k = 0; k < 6; ++k) {
    short8 af = *(const short8*)(hb + c * 200 + k * 32 + g * 8);
#pragma unroll
    for (int t = 0; t < 12; ++t) {
      short8 bfr = *(const short8*)(W2T + (size_t)(t * 16 + c) * NH2 + k * 32 + g * 8);
      acc2[t] = __builtin_amdgcn_mfma_f32_16x16x32_bf16(af, bfr, acc2[t], 0, 0, 0);
    }
  }

  float b3v = b3[0];
#pragma unroll
  for (int r = 0; r < 4; ++r) {
    float sv = 0.f;
#pragma unroll
    for (int t = 0; t < 12; ++t) {
      float h2 = fmaxf(acc2[t][r] + b2[t * 16 + c], 0.f);
      sv = fmaf(h2, W3[t * 16 + c], sv);
    }
    sv += __shfl_xor(sv, 1);
    sv += __shfl_xor(sv, 2);
    sv += __shfl_xor(sv, 4);
    sv += __shfl_xor(sv, 8);
    int row = m0 + g * 4 + r;
    if (c == 0 && wact && row < n) score[row] += sv + b3v;
  }
}

// ---------------- mega: all 6 score branches (sage + 3-layer MLP each) ----------------
// A-frags of Ag and x2_1 loaded ONCE; loops 6 weight sets; i==0 also emits Xb (trunk layer 0)

__global__ __launch_bounds__(256) void k_branches(const unsigned short* __restrict__ Ag,
                                                  const unsigned short* __restrict__ X21,
                                                  const unsigned short* __restrict__ WlT,
                                                  const unsigned short* __restrict__ WrT,
                                                  const float* __restrict__ sbl,
                                                  const unsigned short* __restrict__ W1T, const float* __restrict__ b1,
                                                  const unsigned short* __restrict__ W2T, const float* __restrict__ b2,
                                                  const float* __restrict__ W3, const float* __restrict__ b3,
                                                  unsigned short* __restrict__ Xb, float* __restrict__ score, int n) {
  __shared__ __align__(16) unsigned short sH[4][16 * 200];
  int wid = threadIdx.x >> 6, l = threadIdx.x & 63;
  int m0 = (blockIdx.x * 4 + wid) * 16;
  int c = l & 15, g = l >> 4;
  bool wact = m0 < n;
  int arow = wact ? min(m0 + c, n - 1) : 0;
  size_t aoff = (size_t)arow * NH + g * 8;
  unsigned short* hb = sH[wid];

  short8 agf[3], xf[3];
#pragma unroll
  for (int k = 0; k < 3; ++k) {
    agf[k] = *(const short8*)(Ag + aoff + k * 32);
    xf[k] = *(const short8*)(X21 + aoff + k * 32);
  }
  float sAcc[4] = {0.f, 0.f, 0.f, 0.f};
  float b3v = b3[0];

  for (int i = 0; i < 6; ++i) {
    const unsigned short* wl = WlT + (size_t)i * NH * NH;
    const unsigned short* wr = WrT + (size_t)i * NH * NH;
    const float* bl = sbl + (size_t)i * NH;

    // ---- SAGE GEMM ----
    f32x4 acc[6];
#pragma unroll
    for (int t = 0; t < 6; ++t) acc[t] = (f32x4){0.f, 0.f, 0.f, 0.f};
#pragma unroll
    for (int k = 0; k < 3; ++k) {
#pragma unroll
      for (int t = 0; t < 6; ++t) {
        short8 bfr = *(const short8*)(wl + (size_t)(t * 16 + c) * NH + k * 32 + g * 8);
        acc[t] = __builtin_amdgcn_mfma_f32_16x16x32_bf16(agf[k], bfr, acc[t], 0, 0, 0);
      }
#pragma unroll
      for (int t = 0; t < 6; ++t) {
        short8 bfr = *(const short8*)(wr + (size_t)(t * 16 + c) * NH + k * 32 + g * 8);
        acc[t] = __builtin_amdgcn_mfma_f32_16x16x32_bf16(xf[k], bfr, acc[t], 0, 0, 0);
      }
    }
    // relu + l2norm
    float v[6][4];
#pragma unroll
    for (int t = 0; t < 6; ++t) {
      float bv = bl[t * 16 + c];
#pragma unroll
      for (int r = 0; r < 4; ++r) v[t][r] = fmaxf(acc[t][r] + bv, 0.f);
    }
#pragma unroll
    for (int r = 0; r < 4; ++r) {
      float ss = 0.f;
#pragma unroll
      for (int t = 0; t < 6; ++t) ss = fmaf(v[t][r], v[t][r], ss);
      ss += __shfl_xor(ss, 1);
      ss += __shfl_xor(ss, 2);
      ss += __shfl_xor(ss, 4);
      ss += __shfl_xor(ss, 8);
      float sc = 1.f / fmaxf(sqrtf(ss), 1e-12f);
#pragma unroll
      for (int t = 0; t < 6; ++t) v[t][r] *= sc;
    }
    // i==0 doubles as trunk layer 0 output
    if (i == 0 && wact) {
#pragma unroll
      for (int r = 0; r < 4; ++r) {
        int row = m0 + g * 4 + r;
        if (row < n) {
#pragma unroll
          for (int t = 0; t < 6; ++t) Xb[(size_t)row * NH + t * 16 + c] = f2b(v[t][r]);
        }
      }
    }
    // transpose sage-out into LDS
    __syncthreads();
#pragma unroll
    for (int t = 0; t < 6; ++t)
#pragma unroll
      for (int r = 0; r < 4; ++r)
        hb[(g * 4 + r) * 200 + t * 16 + c] = f2b(v[t][r]);
    __syncthreads();

    // ---- MLP layer 1 ----
    f32x4 acc1[12];
#pragma unroll
    for (int t = 0; t < 12; ++t) acc1[t] = (f32x4){0.f, 0.f, 0.f, 0.f};
#pragma unroll
    for (int k = 0; k < 3; ++k) {
      short8 af = *(const short8*)(hb + c * 200 + k * 32 + g * 8);
#pragma unroll
      for (int t = 0; t < 12; ++t) {
        short8 bfr = *(const short8*)(W1T + (size_t)(t * 16 + c) * NH + k * 32 + g * 8);
        acc1[t] = __builtin_amdgcn_mfma_f32_16x16x32_bf16(af, bfr, acc1[t], 0, 0, 0);
      }
    }
    __syncthreads();
#pragma unroll
    for (int t = 0; t < 12; ++t)
#pragma unroll
      for (int r = 0; r < 4; ++r)
        hb[(g * 4 + r) * 200 + t * 16 + c] = f2b(fmaxf(acc1[t][r] + b1[t * 16 + c], 0.f));
    __syncthreads();

    // ---- MLP layer 2 + 3 ----
    f32x4 acc2[12];
#pragma unroll
    for (int t = 0; t < 12; ++t) acc2[t] = (f32x4){0.f, 0.f, 0.f, 0.f};
#pragma unroll
    for (int k = 0; k < 6; ++k) {
      short8 af = *(const short8*)(hb + c * 200 + k * 32 + g * 8);
#pragma unroll
      for (int t = 0; t < 12; ++t) {
        short8 bfr = *(const short8*)(W2T + (size_t)(t * 16 + c) * NH2 + k * 32 + g * 8);
        acc2[t] = __builtin_amdgcn_mfma_f32_16x16x32_bf16(af, bfr, acc2[t], 0, 0, 0);
      }
    }
#pragma unroll
    for (int r = 0; r < 4; ++r) {
      float sv = 0.f;
#pragma unroll
      for (int t = 0; t < 12; ++t) {
        float h2 = fmaxf(acc2[t][r] + b2[t * 16 + c], 0.f);
        sv = fmaf(h2, W3[t * 16 + c], sv);
      }
      sv += __shfl_xor(sv, 1);
      sv += __shfl_xor(sv, 2);
      sv += __shfl_xor(sv, 4);
      sv += __shfl_xor(sv, 8);
      sAcc[r] += sv + b3v;
    }
  }

#pragma unroll
  for (int r = 0; r < 4; ++r) {
    int row = m0 + g * 4 + r;
    if (c == 0 && wact && row < n) score[row] += sAcc[r];
  }
}

// ---------------- host ----------------

extern "C" void kernel_launch(void* const* d_in, const int* in_sizes, int n_in,
                              void* d_out, int out_size, void* d_ws, size_t ws_size,
                              hipStream_t stream) {
  const int* ei1 = (const int*)d_in[0];
  const float* ev1 = (const float*)d_in[1];
  const int* ei2 = (const int*)d_in[2];
  const float* gW = (const float*)d_in[3];
  const float* gb = (const float*)d_in[4];
  const float* sWl = (const float*)d_in[5];
  const float* sbl = (const float*)d_in[6];
  const float* sWr = (const float*)d_in[7];
  const float* W1 = (const float*)d_in[8];
  const float* b1 = (const float*)d_in[9];
  const float* W2 = (const float*)d_in[10];
  const float* b2 = (const float*)d_in[11];
  const float* W3 = (const float*)d_in[12];
  const float* b3 = (const float*)d_in[13];
  float* score = (float*)d_out;

  const int E = in_sizes[0] / 2;
  const int n = in_sizes[3] / NH;

  const int* d1 = ei1;      // edge_index1[0] = dst
  const int* s1 = ei1 + E;  // edge_index1[1] = src
  const int* s2 = ei2;      // edge_index2[0] = src
  const int* d2 = ei2 + E;  // edge_index2[1] = dst

  char* w = (char*)d_ws;
  auto alloc = [&](size_t bytes) {
    char* p = w;
    w += (bytes + 255) & ~(size_t)255;
    return p;
  };
  int* cnt1 = (int*)alloc((size_t)n * 4);
  int* cnt2 = (int*)alloc((size_t)n * 4);
  int* cur1 = (int*)alloc((size_t)n * 4);
  int* cur2 = (int*)alloc((size_t)n * 4);
  int* rp1 = (int*)alloc((size_t)(n + 1) * 4);
  int* rp2 = (int*)alloc((size_t)(n + 1) * 4);
  int2* c1sv = (int2*)alloc((size_t)E * 8);
  int* c2s = (int*)alloc((size_t)E * 4);
  unsigned short* gwb = (unsigned short*)alloc((size_t)n * NH * 2);
  unsigned short* wlt = (unsigned short*)alloc((size_t)7 * NH * NH * 2);
  unsigned short* wrt = (unsigned short*)alloc((size_t)7 * NH * NH * 2);
  unsigned short* w1t = (unsigned short*)alloc((size_t)NH * NH2 * 2);
  unsigned short* w2t = (unsigned short*)alloc((size_t)NH2 * NH2 * 2);
  unsigned short* x21 = (unsigned short*)alloc((size_t)n * NH * 2);
  unsigned short* Ag = (unsigned short*)alloc((size_t)n * NH * 2);
  unsigned short* xb = (unsigned short*)alloc((size_t)n * NH * 2);
  unsigned short* tb = (unsigned short*)alloc((size_t)n * NH * 2);

  size_t zbytes = (size_t)((char*)cur2 - (char*)cnt1) + (size_t)n * 4;
  hipMemsetAsync(cnt1, 0, zbytes, stream);
  hipMemsetAsync(score, 0, (size_t)n * 4, stream);

  int eb = (E + 255) / 256;
  int nb4 = (n + 3) / 4;          // wave-per-node kernels
  int gblk = (n + 63) / 64;       // 4 MFMA waves (16 rows each) per block

  k_count<<<eb, 256, 0, stream>>>(d1, d2, cnt1, cnt2, E);
  k_scan<<<1, 1024, 0, stream>>>(cnt1, rp1, n);
  k_scan<<<1, 1024, 0, stream>>>(cnt2, rp2, n);
  k_scatter<<<eb, 256, 0, stream>>>(d1, s1, ev1, rp1, cur1, c1sv, s2, d2, rp2, cur2, c2s, E);

  k_cvtgw<<<(n * NH / 4 + 255) / 256, 256, 0, stream>>>(gW, gwb, n * NH);
  k_packw<<<720, 256, 0, stream>>>(sWl, sWr, W1, W2, wlt, wrt, w1t, w2t);

  // x2_1 = l2norm(relu(spmm(adj1, gc1_W) + gc1_b))
  k_gc1<<<nb4, 256, 0, stream>>>(rp1, c1sv, gwb, gb, x21, n);

  // score += mlp(x2_1)
  k_mlp<<<gblk, 256, 0, stream>>>(x21, w1t, b1, w2t, b2, W3, b3, score, n);

  // Ag = mean-agg(x2_1) — reused by trunk layer 0 AND all 6 score branches
  k_agg<<<nb4, 256, 0, stream>>>(rp2, c2s, x21, Ag, n);

  // all 6 score branches fused (emits xb = trunk layer-0 output)
  k_branches<<<gblk, 256, 0, stream>>>(Ag, x21, wlt, wrt, sbl, w1t, b1, w2t, b2, W3, b3, xb, score, n);

  // trunk layers 1..5
  unsigned short* xc = xb;
  unsigned short* xn = tb;
  for (int i = 1; i < 6; ++i) {
    k_agg<<<nb4, 256, 0, stream>>>(rp2, c2s, xc, Ag, n);
    k_sage<0><<<gblk, 256, 0, stream>>>(Ag, wlt + (size_t)i * NH * NH, xc,
                                        wrt + (size_t)i * NH * NH, sbl + (size_t)i * NH, xn, n);
    unsigned short* tmp = xc; xc = xn; xn = tmp;
  }

  // last layer: relu only, then final mlp
  k_agg<<<nb4, 256, 0, stream>>>(rp2, c2s, xc, Ag, n);
  k_sage<1><<<gblk, 256, 0, stream>>>(Ag, wlt + (size_t)6 * NH * NH, xc,
                                      wrt + (size_t)6 * NH * NH, sbl + (size_t)6 * NH, xn, n);
  k_mlp<<<gblk, 256, 0, stream>>>(xn, w1t, b1, w2t, b2, W3, b3, score, n);

  (void)n_in; (void)out_size; (void)ws_size;
}

// Round 4
// 1097.753 us; speedup vs baseline: 2.3564x; 1.2891x over previous
//
#include <hip/hip_runtime.h>

#define NH 96
#define NH2 192

typedef __attribute__((ext_vector_type(8))) short short8;
typedef __attribute__((ext_vector_type(4))) float f32x4;

__device__ __forceinline__ unsigned short f2b(float f) {
  unsigned u = __float_as_uint(f);
  unsigned r = (u + 0x7FFFu + ((u >> 16) & 1u)) >> 16;
  return (unsigned short)r;
}
__device__ __forceinline__ float blo(unsigned w) { return __uint_as_float(w << 16); }
__device__ __forceinline__ float bhi(unsigned w) { return __uint_as_float(w & 0xFFFF0000u); }

// ---------------- CSR build ----------------

__global__ void k_count(const int* __restrict__ dst1, const int* __restrict__ dst2,
                        int* __restrict__ cnt1, int* __restrict__ cnt2, int E) {
  int e = blockIdx.x * blockDim.x + threadIdx.x;
  if (e < E) {
    atomicAdd(&cnt1[dst1[e]], 1);
    atomicAdd(&cnt2[dst2[e]], 1);
  }
}

__global__ __launch_bounds__(1024) void k_scan(const int* __restrict__ cnt, int* __restrict__ rp, int n) {
  __shared__ int s[1024];
  int tid = threadIdx.x;
  int chunk = (n + 1023) >> 10;
  int beg = tid * chunk;
  int end = min(beg + chunk, n);
  int sum = 0;
  for (int i = beg; i < end; ++i) sum += cnt[i];
  s[tid] = sum;
  __syncthreads();
  for (int off = 1; off < 1024; off <<= 1) {
    int v = (tid >= off) ? s[tid - off] : 0;
    __syncthreads();
    s[tid] += v;
    __syncthreads();
  }
  int excl = (tid == 0) ? 0 : s[tid - 1];
  for (int i = beg; i < end; ++i) { rp[i] = excl; excl += cnt[i]; }
  if (tid == 1023) rp[n] = s[1023];
}

__global__ void k_scatter(const int* __restrict__ d1, const int* __restrict__ s1, const float* __restrict__ v1,
                          const int* __restrict__ rp1, int* __restrict__ cur1, int2* __restrict__ c1sv,
                          const int* __restrict__ s2, const int* __restrict__ d2,
                          const int* __restrict__ rp2, int* __restrict__ cur2,
                          int* __restrict__ c2s, int E) {
  int e = blockIdx.x * blockDim.x + threadIdx.x;
  if (e >= E) return;
  {
    int d = d1[e];
    int p = atomicAdd(&cur1[d], 1);
    c1sv[rp1[d] + p] = make_int2(s1[e], __float_as_int(v1[e]));
  }
  {
    int d = d2[e];
    int p = atomicAdd(&cur2[d], 1);
    c2s[rp2[d] + p] = s2[e];
  }
}

// ---------------- weight prep ----------------

__global__ void k_cvtgw(const float* __restrict__ W, unsigned short* __restrict__ Wb, int total) {
  int i = (blockIdx.x * blockDim.x + threadIdx.x) * 4;
  if (i + 3 < total) {
    float4 v = *(const float4*)(W + i);
    ushort4 o;
    o.x = f2b(v.x); o.y = f2b(v.y); o.z = f2b(v.z); o.w = f2b(v.w);
    *(ushort4*)(Wb + i) = o;
  }
}

// pack Wl/Wr (7x96x96), W1 (96x192), W2 (192x192) into transposed [N][K] bf16
__global__ void k_packw(const float* __restrict__ Wl, const float* __restrict__ Wr,
                        const float* __restrict__ W1, const float* __restrict__ W2,
                        unsigned short* __restrict__ WlT, unsigned short* __restrict__ WrT,
                        unsigned short* __restrict__ W1T, unsigned short* __restrict__ W2T) {
  int t = blockIdx.x * blockDim.x + threadIdx.x;
  if (t < 64512) {
    int i = t / 9216, r = t % 9216, nn = r / 96, k = r % 96;
    WlT[t] = f2b(Wl[i * 9216 + k * 96 + nn]);
  } else if (t < 129024) {
    int u = t - 64512;
    int i = u / 9216, r = u % 9216, nn = r / 96, k = r % 96;
    WrT[u] = f2b(Wr[i * 9216 + k * 96 + nn]);
  } else if (t < 147456) {
    int u = t - 129024, nn = u / 96, k = u % 96;
    W1T[u] = f2b(W1[k * 192 + nn]);
  } else if (t < 184320) {
    int u = t - 147456, nn = u / 192, k = u % 192;
    W2T[u] = f2b(W2[k * 192 + nn]);
  }
}

// ---------------- gc1: weighted SPMM + bias + relu + l2norm (unroll-4) ----------------

__global__ __launch_bounds__(256) void k_gc1(const int* __restrict__ rp, const int2* __restrict__ cv,
                                             const unsigned short* __restrict__ Wb,
                                             const float* __restrict__ b, unsigned short* __restrict__ out, int n) {
  int gw = (blockIdx.x * 256 + threadIdx.x) >> 6;
  int l = threadIdx.x & 63;
  if (gw >= n) return;
  int s = rp[gw], e = rp[gw + 1];
  bool act = l < 48;
  float a0 = 0.f, a1 = 0.f, b0 = 0.f, b1 = 0.f, c0 = 0.f, c1 = 0.f, d0 = 0.f, d1 = 0.f;
  int i = s;
  for (; i + 3 < e; i += 4) {
    int2 q0 = cv[i], q1 = cv[i + 1], q2 = cv[i + 2], q3 = cv[i + 3];
    if (act) {
      unsigned w0 = *(const unsigned*)(Wb + (size_t)q0.x * NH + 2 * l);
      unsigned w1 = *(const unsigned*)(Wb + (size_t)q1.x * NH + 2 * l);
      unsigned w2 = *(const unsigned*)(Wb + (size_t)q2.x * NH + 2 * l);
      unsigned w3 = *(const unsigned*)(Wb + (size_t)q3.x * NH + 2 * l);
      float v0 = __int_as_float(q0.y), v1 = __int_as_float(q1.y);
      float v2 = __int_as_float(q2.y), v3 = __int_as_float(q3.y);
      a0 = fmaf(v0, blo(w0), a0); a1 = fmaf(v0, bhi(w0), a1);
      b0 = fmaf(v1, blo(w1), b0); b1 = fmaf(v1, bhi(w1), b1);
      c0 = fmaf(v2, blo(w2), c0); c1 = fmaf(v2, bhi(w2), c1);
      d0 = fmaf(v3, blo(w3), d0); d1 = fmaf(v3, bhi(w3), d1);
    }
  }
  for (; i < e; ++i) {
    int2 q0 = cv[i];
    if (act) {
      unsigned w0 = *(const unsigned*)(Wb + (size_t)q0.x * NH + 2 * l);
      float v0 = __int_as_float(q0.y);
      a0 = fmaf(v0, blo(w0), a0); a1 = fmaf(v0, bhi(w0), a1);
    }
  }
  a0 += b0 + c0 + d0; a1 += b1 + c1 + d1;
  if (act) {
    a0 = fmaxf(a0 + b[2 * l], 0.f);
    a1 = fmaxf(a1 + b[2 * l + 1], 0.f);
  } else { a0 = a1 = 0.f; }
  float ss = a0 * a0 + a1 * a1;
#pragma unroll
  for (int o = 1; o < 64; o <<= 1) ss += __shfl_xor(ss, o);
  float sc = 1.f / fmaxf(sqrtf(ss), 1e-12f);
  if (act) {
    unsigned pk = ((unsigned)f2b(a1 * sc) << 16) | f2b(a0 * sc);
    ((unsigned*)out)[(size_t)gw * 48 + l] = pk;
  }
}

// ---------------- mean aggregation (unroll-4) ----------------

__global__ __launch_bounds__(256) void k_agg(const int* __restrict__ rp, const int* __restrict__ csrc,
                                             const unsigned short* __restrict__ X,
                                             unsigned short* __restrict__ out, int n) {
  int gw = (blockIdx.x * 256 + threadIdx.x) >> 6;
  int l = threadIdx.x & 63;
  if (gw >= n) return;
  int s = rp[gw], e = rp[gw + 1];
  bool act = l < 48;
  float a0 = 0.f, a1 = 0.f, b0 = 0.f, b1 = 0.f, c0 = 0.f, c1 = 0.f, d0 = 0.f, d1 = 0.f;
  int i = s;
  for (; i + 3 < e; i += 4) {
    int s0 = csrc[i], s1 = csrc[i + 1], s2 = csrc[i + 2], s3 = csrc[i + 3];
    if (act) {
      unsigned w0 = *(const unsigned*)(X + (size_t)s0 * NH + 2 * l);
      unsigned w1 = *(const unsigned*)(X + (size_t)s1 * NH + 2 * l);
      unsigned w2 = *(const unsigned*)(X + (size_t)s2 * NH + 2 * l);
      unsigned w3 = *(const unsigned*)(X + (size_t)s3 * NH + 2 * l);
      a0 += blo(w0); a1 += bhi(w0);
      b0 += blo(w1); b1 += bhi(w1);
      c0 += blo(w2); c1 += bhi(w2);
      d0 += blo(w3); d1 += bhi(w3);
    }
  }
  for (; i < e; ++i) {
    int s0 = csrc[i];
    if (act) {
      unsigned w0 = *(const unsigned*)(X + (size_t)s0 * NH + 2 * l);
      a0 += blo(w0); a1 += bhi(w0);
    }
  }
  a0 += b0 + c0 + d0; a1 += b1 + c1 + d1;
  float inv = 1.f / fmaxf((float)(e - s), 1.f);
  if (act) {
    unsigned pk = ((unsigned)f2b(a1 * inv) << 16) | f2b(a0 * inv);
    ((unsigned*)out)[(size_t)gw * 48 + l] = pk;
  }
}

// ---------------- trunk SAGE MFMA GEMM: Y = epi(A@Wl + X@Wr + b) ----------------

template <int EPI>
__global__ __launch_bounds__(256) void k_sage(const unsigned short* __restrict__ A, const unsigned short* __restrict__ WlT,
                                              const unsigned short* __restrict__ X, const unsigned short* __restrict__ WrT,
                                              const float* __restrict__ bias, unsigned short* __restrict__ Y, int n) {
  int wv = blockIdx.x * 4 + (threadIdx.x >> 6);
  int l = threadIdx.x & 63;
  int m0 = wv * 16;
  if (m0 >= n) return;
  int c = l & 15, g = l >> 4;
  int arow = min(m0 + c, n - 1);
  size_t aoff = (size_t)arow * NH + g * 8;

  f32x4 acc[6];
#pragma unroll
  for (int t = 0; t < 6; ++t) acc[t] = (f32x4){0.f, 0.f, 0.f, 0.f};

#pragma unroll
  for (int k = 0; k < 3; ++k) {
    short8 af = *(const short8*)(A + aoff + k * 32);
#pragma unroll
    for (int t = 0; t < 6; ++t) {
      short8 bfr = *(const short8*)(WlT + (size_t)(t * 16 + c) * NH + k * 32 + g * 8);
      acc[t] = __builtin_amdgcn_mfma_f32_16x16x32_bf16(af, bfr, acc[t], 0, 0, 0);
    }
    short8 xf = *(const short8*)(X + aoff + k * 32);
#pragma unroll
    for (int t = 0; t < 6; ++t) {
      short8 bfr = *(const short8*)(WrT + (size_t)(t * 16 + c) * NH + k * 32 + g * 8);
      acc[t] = __builtin_amdgcn_mfma_f32_16x16x32_bf16(xf, bfr, acc[t], 0, 0, 0);
    }
  }

  float v[6][4];
#pragma unroll
  for (int t = 0; t < 6; ++t) {
    float bv = bias[t * 16 + c];
#pragma unroll
    for (int r = 0; r < 4; ++r) v[t][r] = fmaxf(acc[t][r] + bv, 0.f);
  }

  if (EPI == 0) {
#pragma unroll
    for (int r = 0; r < 4; ++r) {
      float ss = 0.f;
#pragma unroll
      for (int t = 0; t < 6; ++t) ss = fmaf(v[t][r], v[t][r], ss);
      ss += __shfl_xor(ss, 1);
      ss += __shfl_xor(ss, 2);
      ss += __shfl_xor(ss, 4);
      ss += __shfl_xor(ss, 8);
      float sc = 1.f / fmaxf(sqrtf(ss), 1e-12f);
#pragma unroll
      for (int t = 0; t < 6; ++t) v[t][r] *= sc;
    }
  }

#pragma unroll
  for (int r = 0; r < 4; ++r) {
    int row = m0 + g * 4 + r;
    if (row < n) {
#pragma unroll
      for (int t = 0; t < 6; ++t) Y[(size_t)row * NH + t * 16 + c] = f2b(v[t][r]);
    }
  }
}

// ---------------- fused 3-layer MLP: score += mlp(X) ----------------

__global__ __launch_bounds__(256) void k_mlp(const unsigned short* __restrict__ X,
                                             const unsigned short* __restrict__ W1T, const float* __restrict__ b1,
                                             const unsigned short* __restrict__ W2T, const float* __restrict__ b2,
                                             const float* __restrict__ W3, const float* __restrict__ b3,
                                             float* __restrict__ score, int n) {
  __shared__ __align__(16) unsigned short sH[4][16 * 200];
  int wid = threadIdx.x >> 6, l = threadIdx.x & 63;
  int m0 = (blockIdx.x * 4 + wid) * 16;
  int c = l & 15, g = l >> 4;
  bool wact = m0 < n;
  int arow = wact ? min(m0 + c, n - 1) : 0;
  unsigned short* hb = sH[wid];

  f32x4 acc1[12];
#pragma unroll
  for (int t = 0; t < 12; ++t) acc1[t] = (f32x4){0.f, 0.f, 0.f, 0.f};
#pragma unroll
  for (int k = 0; k < 3; ++k) {
    short8 af = *(const short8*)(X + (size_t)arow * NH + k * 32 + g * 8);
#pragma unroll
    for (int t = 0; t < 12; ++t) {
      short8 bfr = *(const short8*)(W1T + (size_t)(t * 16 + c) * NH + k * 32 + g * 8);
      acc1[t] = __builtin_amdgcn_mfma_f32_16x16x32_bf16(af, bfr, acc1[t], 0, 0, 0);
    }
  }
#pragma unroll
  for (int t = 0; t < 12; ++t)
#pragma unroll
    for (int r = 0; r < 4; ++r)
      hb[(g * 4 + r) * 200 + t * 16 + c] = f2b(fmaxf(acc1[t][r] + b1[t * 16 + c], 0.f));
  __syncthreads();

  f32x4 acc2[12];
#pragma unroll
  for (int t = 0; t < 12; ++t) acc2[t] = (f32x4){0.f, 0.f, 0.f, 0.f};
#pragma unroll
  for (int k = 0; k < 6; ++k) {
    short8 af = *(const short8*)(hb + c * 200 + k * 32 + g * 8);
#pragma unroll
    for (int t = 0; t < 12; ++t) {
      short8 bfr = *(const short8*)(W2T + (size_t)(t * 16 + c) * NH2 + k * 32 + g * 8);
      acc2[t] = __builtin_amdgcn_mfma_f32_16x16x32_bf16(af, bfr, acc2[t], 0, 0, 0);
    }
  }

  float b3v = b3[0];
#pragma unroll
  for (int r = 0; r < 4; ++r) {
    float sv = 0.f;
#pragma unroll
    for (int t = 0; t < 12; ++t) {
      float h2 = fmaxf(acc2[t][r] + b2[t * 16 + c], 0.f);
      sv = fmaf(h2, W3[t * 16 + c], sv);
    }
    sv += __shfl_xor(sv, 1);
    sv += __shfl_xor(sv, 2);
    sv += __shfl_xor(sv, 4);
    sv += __shfl_xor(sv, 8);
    int row = m0 + g * 4 + r;
    if (c == 0 && wact && row < n) score[row] += sv + b3v;
  }
}

// ---------------- per-branch: sage(Ag,x21;W[i]) -> l2norm -> 3-layer MLP -> atomic score ----------------
// grid.x = 6 * gblk; branch = blockIdx.x / gblk. Branch 0 also emits Xb (trunk layer-0 out).

__global__ __launch_bounds__(256) void k_branch(const unsigned short* __restrict__ Ag,
                                                const unsigned short* __restrict__ X21,
                                                const unsigned short* __restrict__ WlT,
                                                const unsigned short* __restrict__ WrT,
                                                const float* __restrict__ sbl,
                                                const unsigned short* __restrict__ W1T, const float* __restrict__ b1,
                                                const unsigned short* __restrict__ W2T, const float* __restrict__ b2,
                                                const float* __restrict__ W3, const float* __restrict__ b3,
                                                unsigned short* __restrict__ Xb, float* __restrict__ score,
                                                int n, int gblk) {
  __shared__ __align__(16) unsigned short sH[4][16 * 200];
  int bb = blockIdx.x / gblk;
  int blk = blockIdx.x - bb * gblk;
  int wid = threadIdx.x >> 6, l = threadIdx.x & 63;
  int m0 = (blk * 4 + wid) * 16;
  int c = l & 15, g = l >> 4;
  bool wact = m0 < n;
  int arow = wact ? min(m0 + c, n - 1) : 0;
  size_t aoff = (size_t)arow * NH + g * 8;
  unsigned short* hb = sH[wid];

  const unsigned short* wl = WlT + (size_t)bb * NH * NH;
  const unsigned short* wr = WrT + (size_t)bb * NH * NH;
  const float* bl = sbl + (size_t)bb * NH;

  // ---- SAGE GEMM ----
  f32x4 acc[6];
#pragma unroll
  for (int t = 0; t < 6; ++t) acc[t] = (f32x4){0.f, 0.f, 0.f, 0.f};
#pragma unroll
  for (int k = 0; k < 3; ++k) {
    short8 agf = *(const short8*)(Ag + aoff + k * 32);
#pragma unroll
    for (int t = 0; t < 6; ++t) {
      short8 bfr = *(const short8*)(wl + (size_t)(t * 16 + c) * NH + k * 32 + g * 8);
      acc[t] = __builtin_amdgcn_mfma_f32_16x16x32_bf16(agf, bfr, acc[t], 0, 0, 0);
    }
    short8 xf = *(const short8*)(X21 + aoff + k * 32);
#pragma unroll
    for (int t = 0; t < 6; ++t) {
      short8 bfr = *(const short8*)(wr + (size_t)(t * 16 + c) * NH + k * 32 + g * 8);
      acc[t] = __builtin_amdgcn_mfma_f32_16x16x32_bf16(xf, bfr, acc[t], 0, 0, 0);
    }
  }
  // relu + l2norm
  float v[6][4];
#pragma unroll
  for (int t = 0; t < 6; ++t) {
    float bv = bl[t * 16 + c];
#pragma unroll
    for (int r = 0; r < 4; ++r) v[t][r] = fmaxf(acc[t][r] + bv, 0.f);
  }
#pragma unroll
  for (int r = 0; r < 4; ++r) {
    float ss = 0.f;
#pragma unroll
    for (int t = 0; t < 6; ++t) ss = fmaf(v[t][r], v[t][r], ss);
    ss += __shfl_xor(ss, 1);
    ss += __shfl_xor(ss, 2);
    ss += __shfl_xor(ss, 4);
    ss += __shfl_xor(ss, 8);
    float sc = 1.f / fmaxf(sqrtf(ss), 1e-12f);
#pragma unroll
    for (int t = 0; t < 6; ++t) v[t][r] *= sc;
  }
  // branch 0 doubles as trunk layer-0 output
  if (bb == 0 && wact) {
#pragma unroll
    for (int r = 0; r < 4; ++r) {
      int row = m0 + g * 4 + r;
      if (row < n) {
#pragma unroll
        for (int t = 0; t < 6; ++t) Xb[(size_t)row * NH + t * 16 + c] = f2b(v[t][r]);
      }
    }
  }
  // transpose sage-out into LDS (acc dies here -> frees VGPRs)
#pragma unroll
  for (int t = 0; t < 6; ++t)
#pragma unroll
    for (int r = 0; r < 4; ++r)
      hb[(g * 4 + r) * 200 + t * 16 + c] = f2b(v[t][r]);
  __syncthreads();

  // ---- MLP layer 1 ----
  f32x4 acc1[12];
#pragma unroll
  for (int t = 0; t < 12; ++t) acc1[t] = (f32x4){0.f, 0.f, 0.f, 0.f};
#pragma unroll
  for (int k = 0; k < 3; ++k) {
    short8 af = *(const short8*)(hb + c * 200 + k * 32 + g * 8);
#pragma unroll
    for (int t = 0; t < 12; ++t) {
      short8 bfr = *(const short8*)(W1T + (size_t)(t * 16 + c) * NH + k * 32 + g * 8);
      acc1[t] = __builtin_amdgcn_mfma_f32_16x16x32_bf16(af, bfr, acc1[t], 0, 0, 0);
    }
  }
  __syncthreads();
#pragma unroll
  for (int t = 0; t < 12; ++t)
#pragma unroll
    for (int r = 0; r < 4; ++r)
      hb[(g * 4 + r) * 200 + t * 16 + c] = f2b(fmaxf(acc1[t][r] + b1[t * 16 + c], 0.f));
  __syncthreads();

  // ---- MLP layers 2+3 ----
  f32x4 acc2[12];
#pragma unroll
  for (int t = 0; t < 12; ++t) acc2[t] = (f32x4){0.f, 0.f, 0.f, 0.f};
#pragma unroll
  for (int k = 0; k < 6; ++k) {
    short8 af = *(const short8*)(hb + c * 200 + k * 32 + g * 8);
#pragma unroll
    for (int t = 0; t < 12; ++t) {
      short8 bfr = *(const short8*)(W2T + (size_t)(t * 16 + c) * NH2 + k * 32 + g * 8);
      acc2[t] = __builtin_amdgcn_mfma_f32_16x16x32_bf16(af, bfr, acc2[t], 0, 0, 0);
    }
  }
  float b3v = b3[0];
#pragma unroll
  for (int r = 0; r < 4; ++r) {
    float sv = 0.f;
#pragma unroll
    for (int t = 0; t < 12; ++t) {
      float h2 = fmaxf(acc2[t][r] + b2[t * 16 + c], 0.f);
      sv = fmaf(h2, W3[t * 16 + c], sv);
    }
    sv += __shfl_xor(sv, 1);
    sv += __shfl_xor(sv, 2);
    sv += __shfl_xor(sv, 4);
    sv += __shfl_xor(sv, 8);
    int row = m0 + g * 4 + r;
    if (c == 0 && wact && row < n) atomicAdd(&score[row], sv + b3v);
  }
}

// ---------------- host ----------------

extern "C" void kernel_launch(void* const* d_in, const int* in_sizes, int n_in,
                              void* d_out, int out_size, void* d_ws, size_t ws_size,
                              hipStream_t stream) {
  const int* ei1 = (const int*)d_in[0];
  const float* ev1 = (const float*)d_in[1];
  const int* ei2 = (const int*)d_in[2];
  const float* gW = (const float*)d_in[3];
  const float* gb = (const float*)d_in[4];
  const float* sWl = (const float*)d_in[5];
  const float* sbl = (const float*)d_in[6];
  const float* sWr = (const float*)d_in[7];
  const float* W1 = (const float*)d_in[8];
  const float* b1 = (const float*)d_in[9];
  const float* W2 = (const float*)d_in[10];
  const float* b2 = (const float*)d_in[11];
  const float* W3 = (const float*)d_in[12];
  const float* b3 = (const float*)d_in[13];
  float* score = (float*)d_out;

  const int E = in_sizes[0] / 2;
  const int n = in_sizes[3] / NH;

  const int* d1 = ei1;      // edge_index1[0] = dst
  const int* s1 = ei1 + E;  // edge_index1[1] = src
  const int* s2 = ei2;      // edge_index2[0] = src
  const int* d2 = ei2 + E;  // edge_index2[1] = dst

  char* w = (char*)d_ws;
  auto alloc = [&](size_t bytes) {
    char* p = w;
    w += (bytes + 255) & ~(size_t)255;
    return p;
  };
  int* cnt1 = (int*)alloc((size_t)n * 4);
  int* cnt2 = (int*)alloc((size_t)n * 4);
  int* cur1 = (int*)alloc((size_t)n * 4);
  int* cur2 = (int*)alloc((size_t)n * 4);
  int* rp1 = (int*)alloc((size_t)(n + 1) * 4);
  int* rp2 = (int*)alloc((size_t)(n + 1) * 4);
  int2* c1sv = (int2*)alloc((size_t)E * 8);
  int* c2s = (int*)alloc((size_t)E * 4);
  unsigned short* gwb = (unsigned short*)alloc((size_t)n * NH * 2);
  unsigned short* wlt = (unsigned short*)alloc((size_t)7 * NH * NH * 2);
  unsigned short* wrt = (unsigned short*)alloc((size_t)7 * NH * NH * 2);
  unsigned short* w1t = (unsigned short*)alloc((size_t)NH * NH2 * 2);
  unsigned short* w2t = (unsigned short*)alloc((size_t)NH2 * NH2 * 2);
  unsigned short* x21 = (unsigned short*)alloc((size_t)n * NH * 2);
  unsigned short* Ag = (unsigned short*)alloc((size_t)n * NH * 2);
  unsigned short* xb = (unsigned short*)alloc((size_t)n * NH * 2);
  unsigned short* tb = (unsigned short*)alloc((size_t)n * NH * 2);

  size_t zbytes = (size_t)((char*)cur2 - (char*)cnt1) + (size_t)n * 4;
  hipMemsetAsync(cnt1, 0, zbytes, stream);
  hipMemsetAsync(score, 0, (size_t)n * 4, stream);

  int eb = (E + 255) / 256;
  int nb4 = (n + 3) / 4;          // wave-per-node kernels
  int gblk = (n + 63) / 64;       // 4 MFMA waves (16 rows each) per block

  k_count<<<eb, 256, 0, stream>>>(d1, d2, cnt1, cnt2, E);
  k_scan<<<1, 1024, 0, stream>>>(cnt1, rp1, n);
  k_scan<<<1, 1024, 0, stream>>>(cnt2, rp2, n);
  k_scatter<<<eb, 256, 0, stream>>>(d1, s1, ev1, rp1, cur1, c1sv, s2, d2, rp2, cur2, c2s, E);

  k_cvtgw<<<(n * NH / 4 + 255) / 256, 256, 0, stream>>>(gW, gwb, n * NH);
  k_packw<<<720, 256, 0, stream>>>(sWl, sWr, W1, W2, wlt, wrt, w1t, w2t);

  // x2_1 = l2norm(relu(spmm(adj1, gc1_W) + gc1_b))
  k_gc1<<<nb4, 256, 0, stream>>>(rp1, c1sv, gwb, gb, x21, n);

  // score += mlp(x2_1)
  k_mlp<<<gblk, 256, 0, stream>>>(x21, w1t, b1, w2t, b2, W3, b3, score, n);

  // Ag = mean-agg(x2_1) — reused by trunk layer 0 AND all 6 score branches
  k_agg<<<nb4, 256, 0, stream>>>(rp2, c2s, x21, Ag, n);

  // 6 score branches, one per grid slice (branch 0 emits xb = trunk layer-0 out)
  k_branch<<<6 * gblk, 256, 0, stream>>>(Ag, x21, wlt, wrt, sbl, w1t, b1, w2t, b2, W3, b3,
                                         xb, score, n, gblk);

  // trunk layers 1..5
  unsigned short* xc = xb;
  unsigned short* xn = tb;
  for (int i = 1; i < 6; ++i) {
    k_agg<<<nb4, 256, 0, stream>>>(rp2, c2s, xc, Ag, n);
    k_sage<0><<<gblk, 256, 0, stream>>>(Ag, wlt + (size_t)i * NH * NH, xc,
                                        wrt + (size_t)i * NH * NH, sbl + (size_t)i * NH, xn, n);
    unsigned short* tmp = xc; xc = xn; xn = tmp;
  }

  // last layer: relu only, then final mlp
  k_agg<<<nb4, 256, 0, stream>>>(rp2, c2s, xc, Ag, n);
  k_sage<1><<<gblk, 256, 0, stream>>>(Ag, wlt + (size_t)6 * NH * NH, xc,
                                      wrt + (size_t)6 * NH * NH, sbl + (size_t)6 * NH, xn, n);
  k_mlp<<<gblk, 256, 0, stream>>>(xn, w1t, b1, w2t, b2, W3, b3, score, n);

  (void)n_in; (void)out_size; (void)ws_size;
}

// Round 5
// 845.958 us; speedup vs baseline: 3.0577x; 1.2976x over previous
//
#include <hip/hip_runtime.h>

#define NH 96
#define NH2 192

typedef __attribute__((ext_vector_type(8))) short short8;
typedef __attribute__((ext_vector_type(4))) float f32x4;

__device__ __forceinline__ unsigned short f2b(float f) {
  unsigned u = __float_as_uint(f);
  unsigned r = (u + 0x7FFFu + ((u >> 16) & 1u)) >> 16;
  return (unsigned short)r;
}
__device__ __forceinline__ float blo(unsigned w) { return __uint_as_float(w << 16); }
__device__ __forceinline__ float bhi(unsigned w) { return __uint_as_float(w & 0xFFFF0000u); }
__device__ __forceinline__ float b2f(short v) { return __uint_as_float(((unsigned)(unsigned short)v) << 16); }

// ---------------- CSR build ----------------

__global__ void k_count(const int* __restrict__ dst1, const int* __restrict__ dst2,
                        int* __restrict__ cnt1, int* __restrict__ cnt2, int E) {
  int e = blockIdx.x * blockDim.x + threadIdx.x;
  if (e < E) {
    atomicAdd(&cnt1[dst1[e]], 1);
    atomicAdd(&cnt2[dst2[e]], 1);
  }
}

__global__ __launch_bounds__(1024) void k_scan(const int* __restrict__ cnt, int* __restrict__ rp, int n) {
  __shared__ int s[1024];
  int tid = threadIdx.x;
  int chunk = (n + 1023) >> 10;
  int beg = tid * chunk;
  int end = min(beg + chunk, n);
  int sum = 0;
  for (int i = beg; i < end; ++i) sum += cnt[i];
  s[tid] = sum;
  __syncthreads();
  for (int off = 1; off < 1024; off <<= 1) {
    int v = (tid >= off) ? s[tid - off] : 0;
    __syncthreads();
    s[tid] += v;
    __syncthreads();
  }
  int excl = (tid == 0) ? 0 : s[tid - 1];
  for (int i = beg; i < end; ++i) { rp[i] = excl; excl += cnt[i]; }
  if (tid == 1023) rp[n] = s[1023];
}

__global__ void k_scatter(const int* __restrict__ d1, const int* __restrict__ s1, const float* __restrict__ v1,
                          const int* __restrict__ rp1, int* __restrict__ cur1, int2* __restrict__ c1sv,
                          const int* __restrict__ s2, const int* __restrict__ d2,
                          const int* __restrict__ rp2, int* __restrict__ cur2,
                          int* __restrict__ c2s, int E) {
  int e = blockIdx.x * blockDim.x + threadIdx.x;
  if (e >= E) return;
  {
    int d = d1[e];
    int p = atomicAdd(&cur1[d], 1);
    c1sv[rp1[d] + p] = make_int2(s1[e], __float_as_int(v1[e]));
  }
  {
    int d = d2[e];
    int p = atomicAdd(&cur2[d], 1);
    c2s[rp2[d] + p] = s2[e];
  }
}

// ---------------- weight prep ----------------

__global__ void k_cvtgw(const float* __restrict__ W, unsigned short* __restrict__ Wb, int total) {
  int i = (blockIdx.x * blockDim.x + threadIdx.x) * 4;
  if (i + 3 < total) {
    float4 v = *(const float4*)(W + i);
    ushort4 o;
    o.x = f2b(v.x); o.y = f2b(v.y); o.z = f2b(v.z); o.w = f2b(v.w);
    *(ushort4*)(Wb + i) = o;
  }
}

// Pack weights into MFMA B-fragment order: frag(t,kf) at [(t*NKF+kf)*512 + lane*8 + j],
// value = W[k][nn] with k = kf*32 + (lane>>4)*8 + j, nn = t*16 + (lane&15).
// Wl/Wr: 7 x (6t x 3kf); W1: 12t x 3kf; W2: 12t x 6kf.
__global__ void k_packw(const float* __restrict__ Wl, const float* __restrict__ Wr,
                        const float* __restrict__ W1, const float* __restrict__ W2,
                        unsigned short* __restrict__ Wlp, unsigned short* __restrict__ Wrp,
                        unsigned short* __restrict__ W1p, unsigned short* __restrict__ W2p) {
  int t = blockIdx.x * blockDim.x + threadIdx.x;
  if (t < 129024) {                         // Wl then Wr: 7 * 9216 each
    bool isR = t >= 64512;
    int u = isR ? t - 64512 : t;
    int i = u / 9216, v = u % 9216;
    int tt = v / 1536, r = v % 1536;
    int kf = r / 512, w = r % 512, l = w >> 3, j = w & 7;
    int c = l & 15, g = l >> 4;
    int k = kf * 32 + g * 8 + j, nn = tt * 16 + c;
    float val = (isR ? Wr : Wl)[i * 9216 + k * 96 + nn];
    (isR ? Wrp : Wlp)[u] = f2b(val);
  } else if (t < 147456) {                  // W1: 12t x 3kf = 18432
    int u = t - 129024;
    int tt = u / 1536, r = u % 1536;
    int kf = r / 512, w = r % 512, l = w >> 3, j = w & 7;
    int c = l & 15, g = l >> 4;
    int k = kf * 32 + g * 8 + j, nn = tt * 16 + c;
    W1p[u] = f2b(W1[k * 192 + nn]);
  } else if (t < 184320) {                  // W2: 12t x 6kf = 36864
    int u = t - 147456;
    int tt = u / 3072, r = u % 3072;
    int kf = r / 512, w = r % 512, l = w >> 3, j = w & 7;
    int c = l & 15, g = l >> 4;
    int k = kf * 32 + g * 8 + j, nn = tt * 16 + c;
    W2p[u] = f2b(W2[k * 192 + nn]);
  }
}

// ---------------- gc1: weighted SPMM + bias + relu + l2norm (unroll-4) ----------------

__global__ __launch_bounds__(256) void k_gc1(const int* __restrict__ rp, const int2* __restrict__ cv,
                                             const unsigned short* __restrict__ Wb,
                                             const float* __restrict__ b, unsigned short* __restrict__ out, int n) {
  int gw = (blockIdx.x * 256 + threadIdx.x) >> 6;
  int l = threadIdx.x & 63;
  if (gw >= n) return;
  int s = rp[gw], e = rp[gw + 1];
  bool act = l < 48;
  float a0 = 0.f, a1 = 0.f, b0 = 0.f, b1 = 0.f, c0 = 0.f, c1 = 0.f, d0 = 0.f, d1 = 0.f;
  int i = s;
  for (; i + 3 < e; i += 4) {
    int2 q0 = cv[i], q1 = cv[i + 1], q2 = cv[i + 2], q3 = cv[i + 3];
    if (act) {
      unsigned w0 = *(const unsigned*)(Wb + (size_t)q0.x * NH + 2 * l);
      unsigned w1 = *(const unsigned*)(Wb + (size_t)q1.x * NH + 2 * l);
      unsigned w2 = *(const unsigned*)(Wb + (size_t)q2.x * NH + 2 * l);
      unsigned w3 = *(const unsigned*)(Wb + (size_t)q3.x * NH + 2 * l);
      float v0 = __int_as_float(q0.y), v1 = __int_as_float(q1.y);
      float v2 = __int_as_float(q2.y), v3 = __int_as_float(q3.y);
      a0 = fmaf(v0, blo(w0), a0); a1 = fmaf(v0, bhi(w0), a1);
      b0 = fmaf(v1, blo(w1), b0); b1 = fmaf(v1, bhi(w1), b1);
      c0 = fmaf(v2, blo(w2), c0); c1 = fmaf(v2, bhi(w2), c1);
      d0 = fmaf(v3, blo(w3), d0); d1 = fmaf(v3, bhi(w3), d1);
    }
  }
  for (; i < e; ++i) {
    int2 q0 = cv[i];
    if (act) {
      unsigned w0 = *(const unsigned*)(Wb + (size_t)q0.x * NH + 2 * l);
      float v0 = __int_as_float(q0.y);
      a0 = fmaf(v0, blo(w0), a0); a1 = fmaf(v0, bhi(w0), a1);
    }
  }
  a0 += b0 + c0 + d0; a1 += b1 + c1 + d1;
  if (act) {
    a0 = fmaxf(a0 + b[2 * l], 0.f);
    a1 = fmaxf(a1 + b[2 * l + 1], 0.f);
  } else { a0 = a1 = 0.f; }
  float ss = a0 * a0 + a1 * a1;
#pragma unroll
  for (int o = 1; o < 64; o <<= 1) ss += __shfl_xor(ss, o);
  float sc = 1.f / fmaxf(sqrtf(ss), 1e-12f);
  if (act) {
    unsigned pk = ((unsigned)f2b(a1 * sc) << 16) | f2b(a0 * sc);
    ((unsigned*)out)[(size_t)gw * 48 + l] = pk;
  }
}

// ---------------- mean aggregation (unroll-4) — used once, for the shared branch input ----------------

__global__ __launch_bounds__(256) void k_agg(const int* __restrict__ rp, const int* __restrict__ csrc,
                                             const unsigned short* __restrict__ X,
                                             unsigned short* __restrict__ out, int n) {
  int gw = (blockIdx.x * 256 + threadIdx.x) >> 6;
  int l = threadIdx.x & 63;
  if (gw >= n) return;
  int s = rp[gw], e = rp[gw + 1];
  bool act = l < 48;
  float a0 = 0.f, a1 = 0.f, b0 = 0.f, b1 = 0.f, c0 = 0.f, c1 = 0.f, d0 = 0.f, d1 = 0.f;
  int i = s;
  for (; i + 3 < e; i += 4) {
    int s0 = csrc[i], s1 = csrc[i + 1], s2 = csrc[i + 2], s3 = csrc[i + 3];
    if (act) {
      unsigned w0 = *(const unsigned*)(X + (size_t)s0 * NH + 2 * l);
      unsigned w1 = *(const unsigned*)(X + (size_t)s1 * NH + 2 * l);
      unsigned w2 = *(const unsigned*)(X + (size_t)s2 * NH + 2 * l);
      unsigned w3 = *(const unsigned*)(X + (size_t)s3 * NH + 2 * l);
      a0 += blo(w0); a1 += bhi(w0);
      b0 += blo(w1); b1 += bhi(w1);
      c0 += blo(w2); c1 += bhi(w2);
      d0 += blo(w3); d1 += bhi(w3);
    }
  }
  for (; i < e; ++i) {
    int s0 = csrc[i];
    if (act) {
      unsigned w0 = *(const unsigned*)(X + (size_t)s0 * NH + 2 * l);
      a0 += blo(w0); a1 += bhi(w0);
    }
  }
  a0 += b0 + c0 + d0; a1 += b1 + c1 + d1;
  float inv = 1.f / fmaxf((float)(e - s), 1.f);
  if (act) {
    unsigned pk = ((unsigned)f2b(a1 * inv) << 16) | f2b(a0 * inv);
    ((unsigned*)out)[(size_t)gw * 48 + l] = pk;
  }
}

// ---------------- trunk fused agg+SAGE: Y = epi(mean_nbr(X)@Wl + X@Wr + b) ----------------
// Lane (c,g) gathers+averages neighbor chunks of node m0+c directly into the A-fragment.

template <int EPI>
__global__ __launch_bounds__(256) void k_sageagg(const int* __restrict__ rp, const int* __restrict__ csrc,
                                                 const unsigned short* __restrict__ X,
                                                 const unsigned short* __restrict__ Wlp,
                                                 const unsigned short* __restrict__ Wrp,
                                                 const float* __restrict__ bias,
                                                 unsigned short* __restrict__ Y, int n) {
  int wv = blockIdx.x * 4 + (threadIdx.x >> 6);
  int l = threadIdx.x & 63;
  int m0 = wv * 16;
  if (m0 >= n) return;
  int c = l & 15, g = l >> 4;
  int nd = min(m0 + c, n - 1);
  int s = rp[nd], e = rp[nd + 1];

  // gather-mean into fp32 (24 elems/lane = cols {kf*32+g*8..+8})
  float aa[3][8];
#pragma unroll
  for (int kf = 0; kf < 3; ++kf)
#pragma unroll
    for (int j = 0; j < 8; ++j) aa[kf][j] = 0.f;

  const unsigned short* Xg = X + g * 8;
  for (int i = s; i < e; ++i) {
    const unsigned short* xr = Xg + (size_t)csrc[i] * NH;
    short8 v0 = *(const short8*)(xr);
    short8 v1 = *(const short8*)(xr + 32);
    short8 v2 = *(const short8*)(xr + 64);
#pragma unroll
    for (int j = 0; j < 8; ++j) {
      aa[0][j] += b2f(v0[j]);
      aa[1][j] += b2f(v1[j]);
      aa[2][j] += b2f(v2[j]);
    }
  }
  float inv = 1.f / fmaxf((float)(e - s), 1.f);
  short8 af[3];
#pragma unroll
  for (int kf = 0; kf < 3; ++kf)
#pragma unroll
    for (int j = 0; j < 8; ++j) af[kf][j] = (short)f2b(aa[kf][j] * inv);

  // X-side (lin_r) fragments, row-major
  size_t aoff = (size_t)nd * NH + g * 8;
  short8 xf[3];
#pragma unroll
  for (int kf = 0; kf < 3; ++kf) xf[kf] = *(const short8*)(X + aoff + kf * 32);

  f32x4 acc[6];
#pragma unroll
  for (int t = 0; t < 6; ++t) acc[t] = (f32x4){0.f, 0.f, 0.f, 0.f};
#pragma unroll
  for (int kf = 0; kf < 3; ++kf) {
#pragma unroll
    for (int t = 0; t < 6; ++t) {
      short8 bl_ = *(const short8*)(Wlp + ((t * 3 + kf) << 9) + (l << 3));
      acc[t] = __builtin_amdgcn_mfma_f32_16x16x32_bf16(af[kf], bl_, acc[t], 0, 0, 0);
    }
#pragma unroll
    for (int t = 0; t < 6; ++t) {
      short8 br_ = *(const short8*)(Wrp + ((t * 3 + kf) << 9) + (l << 3));
      acc[t] = __builtin_amdgcn_mfma_f32_16x16x32_bf16(xf[kf], br_, acc[t], 0, 0, 0);
    }
  }

  float v[6][4];
#pragma unroll
  for (int t = 0; t < 6; ++t) {
    float bv = bias[t * 16 + c];
#pragma unroll
    for (int r = 0; r < 4; ++r) v[t][r] = fmaxf(acc[t][r] + bv, 0.f);
  }
  if (EPI == 0) {
#pragma unroll
    for (int r = 0; r < 4; ++r) {
      float ss = 0.f;
#pragma unroll
      for (int t = 0; t < 6; ++t) ss = fmaf(v[t][r], v[t][r], ss);
      ss += __shfl_xor(ss, 1);
      ss += __shfl_xor(ss, 2);
      ss += __shfl_xor(ss, 4);
      ss += __shfl_xor(ss, 8);
      float sc = 1.f / fmaxf(sqrtf(ss), 1e-12f);
#pragma unroll
      for (int t = 0; t < 6; ++t) v[t][r] *= sc;
    }
  }
#pragma unroll
  for (int r = 0; r < 4; ++r) {
    int row = m0 + g * 4 + r;
    if (row < n) {
#pragma unroll
      for (int t = 0; t < 6; ++t) Y[(size_t)row * NH + t * 16 + c] = f2b(v[t][r]);
    }
  }
}

// ---------------- fused 3-layer MLP: score += mlp(X) ----------------

__global__ __launch_bounds__(256) void k_mlp(const unsigned short* __restrict__ X,
                                             const unsigned short* __restrict__ W1p, const float* __restrict__ b1,
                                             const unsigned short* __restrict__ W2p, const float* __restrict__ b2,
                                             const float* __restrict__ W3, const float* __restrict__ b3,
                                             float* __restrict__ score, int n) {
  __shared__ __align__(16) unsigned short sH[4][16 * 200];
  int wid = threadIdx.x >> 6, l = threadIdx.x & 63;
  int m0 = (blockIdx.x * 4 + wid) * 16;
  int c = l & 15, g = l >> 4;
  bool wact = m0 < n;
  int arow = wact ? min(m0 + c, n - 1) : 0;
  unsigned short* hb = sH[wid];

  f32x4 acc1[12];
#pragma unroll
  for (int t = 0; t < 12; ++t) acc1[t] = (f32x4){0.f, 0.f, 0.f, 0.f};
#pragma unroll
  for (int kf = 0; kf < 3; ++kf) {
    short8 af = *(const short8*)(X + (size_t)arow * NH + kf * 32 + g * 8);
#pragma unroll
    for (int t = 0; t < 12; ++t) {
      short8 bfr = *(const short8*)(W1p + ((t * 3 + kf) << 9) + (l << 3));
      acc1[t] = __builtin_amdgcn_mfma_f32_16x16x32_bf16(af, bfr, acc1[t], 0, 0, 0);
    }
  }
#pragma unroll
  for (int t = 0; t < 12; ++t)
#pragma unroll
    for (int r = 0; r < 4; ++r)
      hb[(g * 4 + r) * 200 + t * 16 + c] = f2b(fmaxf(acc1[t][r] + b1[t * 16 + c], 0.f));
  __syncthreads();

  f32x4 acc2[12];
#pragma unroll
  for (int t = 0; t < 12; ++t) acc2[t] = (f32x4){0.f, 0.f, 0.f, 0.f};
#pragma unroll
  for (int kf = 0; kf < 6; ++kf) {
    short8 af = *(const short8*)(hb + c * 200 + kf * 32 + g * 8);
#pragma unroll
    for (int t = 0; t < 12; ++t) {
      short8 bfr = *(const short8*)(W2p + ((t * 6 + kf) << 9) + (l << 3));
      acc2[t] = __builtin_amdgcn_mfma_f32_16x16x32_bf16(af, bfr, acc2[t], 0, 0, 0);
    }
  }

  float b3v = b3[0];
#pragma unroll
  for (int r = 0; r < 4; ++r) {
    float sv = 0.f;
#pragma unroll
    for (int t = 0; t < 12; ++t) {
      float h2 = fmaxf(acc2[t][r] + b2[t * 16 + c], 0.f);
      sv = fmaf(h2, W3[t * 16 + c], sv);
    }
    sv += __shfl_xor(sv, 1);
    sv += __shfl_xor(sv, 2);
    sv += __shfl_xor(sv, 4);
    sv += __shfl_xor(sv, 8);
    int row = m0 + g * 4 + r;
    if (c == 0 && wact && row < n) score[row] += sv + b3v;
  }
}

// ---------------- per-branch: sage(Ag,x21;W[i]) -> l2norm -> 3-layer MLP -> atomic score ----------------

__global__ __launch_bounds__(256) void k_branch(const unsigned short* __restrict__ Ag,
                                                const unsigned short* __restrict__ X21,
                                                const unsigned short* __restrict__ Wlp,
                                                const unsigned short* __restrict__ Wrp,
                                                const float* __restrict__ sbl,
                                                const unsigned short* __restrict__ W1p, const float* __restrict__ b1,
                                                const unsigned short* __restrict__ W2p, const float* __restrict__ b2,
                                                const float* __restrict__ W3, const float* __restrict__ b3,
                                                unsigned short* __restrict__ Xb, float* __restrict__ score,
                                                int n, int gblk) {
  __shared__ __align__(16) unsigned short sH[4][16 * 200];
  int bb = blockIdx.x / gblk;
  int blk = blockIdx.x - bb * gblk;
  int wid = threadIdx.x >> 6, l = threadIdx.x & 63;
  int m0 = (blk * 4 + wid) * 16;
  int c = l & 15, g = l >> 4;
  bool wact = m0 < n;
  int arow = wact ? min(m0 + c, n - 1) : 0;
  size_t aoff = (size_t)arow * NH + g * 8;
  unsigned short* hb = sH[wid];

  const unsigned short* wl = Wlp + (size_t)bb * 9216;
  const unsigned short* wr = Wrp + (size_t)bb * 9216;
  const float* bl = sbl + (size_t)bb * NH;

  // ---- SAGE GEMM ----
  f32x4 acc[6];
#pragma unroll
  for (int t = 0; t < 6; ++t) acc[t] = (f32x4){0.f, 0.f, 0.f, 0.f};
#pragma unroll
  for (int kf = 0; kf < 3; ++kf) {
    short8 agf = *(const short8*)(Ag + aoff + kf * 32);
#pragma unroll
    for (int t = 0; t < 6; ++t) {
      short8 bfr = *(const short8*)(wl + ((t * 3 + kf) << 9) + (l << 3));
      acc[t] = __builtin_amdgcn_mfma_f32_16x16x32_bf16(agf, bfr, acc[t], 0, 0, 0);
    }
    short8 xf = *(const short8*)(X21 + aoff + kf * 32);
#pragma unroll
    for (int t = 0; t < 6; ++t) {
      short8 bfr = *(const short8*)(wr + ((t * 3 + kf) << 9) + (l << 3));
      acc[t] = __builtin_amdgcn_mfma_f32_16x16x32_bf16(xf, bfr, acc[t], 0, 0, 0);
    }
  }
  // relu + l2norm
  float v[6][4];
#pragma unroll
  for (int t = 0; t < 6; ++t) {
    float bv = bl[t * 16 + c];
#pragma unroll
    for (int r = 0; r < 4; ++r) v[t][r] = fmaxf(acc[t][r] + bv, 0.f);
  }
#pragma unroll
  for (int r = 0; r < 4; ++r) {
    float ss = 0.f;
#pragma unroll
    for (int t = 0; t < 6; ++t) ss = fmaf(v[t][r], v[t][r], ss);
    ss += __shfl_xor(ss, 1);
    ss += __shfl_xor(ss, 2);
    ss += __shfl_xor(ss, 4);
    ss += __shfl_xor(ss, 8);
    float sc = 1.f / fmaxf(sqrtf(ss), 1e-12f);
#pragma unroll
    for (int t = 0; t < 6; ++t) v[t][r] *= sc;
  }
  if (bb == 0 && wact) {
#pragma unroll
    for (int r = 0; r < 4; ++r) {
      int row = m0 + g * 4 + r;
      if (row < n) {
#pragma unroll
        for (int t = 0; t < 6; ++t) Xb[(size_t)row * NH + t * 16 + c] = f2b(v[t][r]);
      }
    }
  }
#pragma unroll
  for (int t = 0; t < 6; ++t)
#pragma unroll
    for (int r = 0; r < 4; ++r)
      hb[(g * 4 + r) * 200 + t * 16 + c] = f2b(v[t][r]);
  __syncthreads();

  // ---- MLP layer 1 ----
  f32x4 acc1[12];
#pragma unroll
  for (int t = 0; t < 12; ++t) acc1[t] = (f32x4){0.f, 0.f, 0.f, 0.f};
#pragma unroll
  for (int kf = 0; kf < 3; ++kf) {
    short8 af = *(const short8*)(hb + c * 200 + kf * 32 + g * 8);
#pragma unroll
    for (int t = 0; t < 12; ++t) {
      short8 bfr = *(const short8*)(W1p + ((t * 3 + kf) << 9) + (l << 3));
      acc1[t] = __builtin_amdgcn_mfma_f32_16x16x32_bf16(af, bfr, acc1[t], 0, 0, 0);
    }
  }
  __syncthreads();
#pragma unroll
  for (int t = 0; t < 12; ++t)
#pragma unroll
    for (int r = 0; r < 4; ++r)
      hb[(g * 4 + r) * 200 + t * 16 + c] = f2b(fmaxf(acc1[t][r] + b1[t * 16 + c], 0.f));
  __syncthreads();

  // ---- MLP layers 2+3 ----
  f32x4 acc2[12];
#pragma unroll
  for (int t = 0; t < 12; ++t) acc2[t] = (f32x4){0.f, 0.f, 0.f, 0.f};
#pragma unroll
  for (int kf = 0; kf < 6; ++kf) {
    short8 af = *(const short8*)(hb + c * 200 + kf * 32 + g * 8);
#pragma unroll
    for (int t = 0; t < 12; ++t) {
      short8 bfr = *(const short8*)(W2p + ((t * 6 + kf) << 9) + (l << 3));
      acc2[t] = __builtin_amdgcn_mfma_f32_16x16x32_bf16(af, bfr, acc2[t], 0, 0, 0);
    }
  }
  float b3v = b3[0];
#pragma unroll
  for (int r = 0; r < 4; ++r) {
    float sv = 0.f;
#pragma unroll
    for (int t = 0; t < 12; ++t) {
      float h2 = fmaxf(acc2[t][r] + b2[t * 16 + c], 0.f);
      sv = fmaf(h2, W3[t * 16 + c], sv);
    }
    sv += __shfl_xor(sv, 1);
    sv += __shfl_xor(sv, 2);
    sv += __shfl_xor(sv, 4);
    sv += __shfl_xor(sv, 8);
    int row = m0 + g * 4 + r;
    if (c == 0 && wact && row < n) atomicAdd(&score[row], sv + b3v);
  }
}

// ---------------- host ----------------

extern "C" void kernel_launch(void* const* d_in, const int* in_sizes, int n_in,
                              void* d_out, int out_size, void* d_ws, size_t ws_size,
                              hipStream_t stream) {
  const int* ei1 = (const int*)d_in[0];
  const float* ev1 = (const float*)d_in[1];
  const int* ei2 = (const int*)d_in[2];
  const float* gW = (const float*)d_in[3];
  const float* gb = (const float*)d_in[4];
  const float* sWl = (const float*)d_in[5];
  const float* sbl = (const float*)d_in[6];
  const float* sWr = (const float*)d_in[7];
  const float* W1 = (const float*)d_in[8];
  const float* b1 = (const float*)d_in[9];
  const float* W2 = (const float*)d_in[10];
  const float* b2 = (const float*)d_in[11];
  const float* W3 = (const float*)d_in[12];
  const float* b3 = (const float*)d_in[13];
  float* score = (float*)d_out;

  const int E = in_sizes[0] / 2;
  const int n = in_sizes[3] / NH;

  const int* d1 = ei1;      // edge_index1[0] = dst
  const int* s1 = ei1 + E;  // edge_index1[1] = src
  const int* s2 = ei2;      // edge_index2[0] = src
  const int* d2 = ei2 + E;  // edge_index2[1] = dst

  char* w = (char*)d_ws;
  auto alloc = [&](size_t bytes) {
    char* p = w;
    w += (bytes + 255) & ~(size_t)255;
    return p;
  };
  int* cnt1 = (int*)alloc((size_t)n * 4);
  int* cnt2 = (int*)alloc((size_t)n * 4);
  int* cur1 = (int*)alloc((size_t)n * 4);
  int* cur2 = (int*)alloc((size_t)n * 4);
  int* rp1 = (int*)alloc((size_t)(n + 1) * 4);
  int* rp2 = (int*)alloc((size_t)(n + 1) * 4);
  int2* c1sv = (int2*)alloc((size_t)E * 8);
  int* c2s = (int*)alloc((size_t)E * 4);
  unsigned short* gwb = (unsigned short*)alloc((size_t)n * NH * 2);
  unsigned short* wlp = (unsigned short*)alloc((size_t)7 * NH * NH * 2);
  unsigned short* wrp = (unsigned short*)alloc((size_t)7 * NH * NH * 2);
  unsigned short* w1p = (unsigned short*)alloc((size_t)NH * NH2 * 2);
  unsigned short* w2p = (unsigned short*)alloc((size_t)NH2 * NH2 * 2);
  unsigned short* x21 = (unsigned short*)alloc((size_t)n * NH * 2);
  unsigned short* Ag = (unsigned short*)alloc((size_t)n * NH * 2);
  unsigned short* xb = (unsigned short*)alloc((size_t)n * NH * 2);
  unsigned short* tb = (unsigned short*)alloc((size_t)n * NH * 2);

  size_t zbytes = (size_t)((char*)cur2 - (char*)cnt1) + (size_t)n * 4;
  hipMemsetAsync(cnt1, 0, zbytes, stream);
  hipMemsetAsync(score, 0, (size_t)n * 4, stream);

  int eb = (E + 255) / 256;
  int nb4 = (n + 3) / 4;          // wave-per-node kernels
  int gblk = (n + 63) / 64;       // 4 MFMA waves (16 rows each) per block

  k_count<<<eb, 256, 0, stream>>>(d1, d2, cnt1, cnt2, E);
  k_scan<<<1, 1024, 0, stream>>>(cnt1, rp1, n);
  k_scan<<<1, 1024, 0, stream>>>(cnt2, rp2, n);
  k_scatter<<<eb, 256, 0, stream>>>(d1, s1, ev1, rp1, cur1, c1sv, s2, d2, rp2, cur2, c2s, E);

  k_cvtgw<<<(n * NH / 4 + 255) / 256, 256, 0, stream>>>(gW, gwb, n * NH);
  k_packw<<<720, 256, 0, stream>>>(sWl, sWr, W1, W2, wlp, wrp, w1p, w2p);

  // x2_1 = l2norm(relu(spmm(adj1, gc1_W) + gc1_b))
  k_gc1<<<nb4, 256, 0, stream>>>(rp1, c1sv, gwb, gb, x21, n);

  // score += mlp(x2_1)
  k_mlp<<<gblk, 256, 0, stream>>>(x21, w1p, b1, w2p, b2, W3, b3, score, n);

  // Ag = mean-agg(x2_1) — shared by all 6 score branches (incl. trunk layer 0)
  k_agg<<<nb4, 256, 0, stream>>>(rp2, c2s, x21, Ag, n);

  // 6 score branches, one per grid slice (branch 0 emits xb = trunk layer-0 out)
  k_branch<<<6 * gblk, 256, 0, stream>>>(Ag, x21, wlp, wrp, sbl, w1p, b1, w2p, b2, W3, b3,
                                         xb, score, n, gblk);

  // trunk layers 1..5 (fused agg+sage)
  unsigned short* xc = xb;
  unsigned short* xn = tb;
  for (int i = 1; i < 6; ++i) {
    k_sageagg<0><<<gblk, 256, 0, stream>>>(rp2, c2s, xc, wlp + (size_t)i * 9216,
                                           wrp + (size_t)i * 9216, sbl + (size_t)i * NH, xn, n);
    unsigned short* tmp = xc; xc = xn; xn = tmp;
  }

  // last layer: relu only, then final mlp
  k_sageagg<1><<<gblk, 256, 0, stream>>>(rp2, c2s, xc, wlp + (size_t)6 * 9216,
                                         wrp + (size_t)6 * 9216, sbl + (size_t)6 * NH, xn, n);
  k_mlp<<<gblk, 256, 0, stream>>>(xn, w1p, b1, w2p, b2, W3, b3, score, n);

  (void)n_in; (void)out_size; (void)ws_size;
}

// Round 6
// 837.659 us; speedup vs baseline: 3.0880x; 1.0099x over previous
//
#include <hip/hip_runtime.h>

#define NH 96
#define NH2 192

typedef __attribute__((ext_vector_type(8))) short short8;
typedef __attribute__((ext_vector_type(4))) float f32x4;

__device__ __forceinline__ unsigned short f2b(float f) {
  unsigned u = __float_as_uint(f);
  unsigned r = (u + 0x7FFFu + ((u >> 16) & 1u)) >> 16;
  return (unsigned short)r;
}
__device__ __forceinline__ float blo(unsigned w) { return __uint_as_float(w << 16); }
__device__ __forceinline__ float bhi(unsigned w) { return __uint_as_float(w & 0xFFFF0000u); }
__device__ __forceinline__ float b2f(short v) { return __uint_as_float(((unsigned)(unsigned short)v) << 16); }

__device__ __forceinline__ unsigned cvt_pk(float lo, float hi) {
  unsigned r;
  asm("v_cvt_pk_bf16_f32 %0, %1, %2" : "=v"(r) : "v"(lo), "v"(hi));
  return r;
}

__device__ __forceinline__ short8 u4_to_s8(int a, int b, int c, int d) {
  union { int u[4]; short8 s; } x;
  x.u[0] = a; x.u[1] = b; x.u[2] = c; x.u[3] = d;
  return x.s;
}

#define MFMA(a, b, c) __builtin_amdgcn_mfma_f32_16x16x32_bf16((a), (b), (c), 0, 0, 0)

// cross-g exchange: target lane (c,g) builds B-fragment elems H[c][kf*32+g*8+j]
// from source values held as (t = 2kf+ (g>>1), reg r) in lanes (c, 2*(g&1)(+1)).
__device__ __forceinline__ short8 xchg(unsigned p0lo, unsigned p0hi, unsigned p1lo, unsigned p1hi,
                                       int srcA, int srcB, int hi) {
  int a0 = __shfl((int)p0lo, srcA), a1 = __shfl((int)p0hi, srcA);
  int c0 = __shfl((int)p1lo, srcA), c1 = __shfl((int)p1hi, srcA);
  int b0 = __shfl((int)p0lo, srcB), b1 = __shfl((int)p0hi, srcB);
  int d0 = __shfl((int)p1lo, srcB), d1 = __shfl((int)p1hi, srcB);
  return u4_to_s8(hi ? c0 : a0, hi ? c1 : a1, hi ? d0 : b0, hi ? d1 : b1);
}

// ---------------- CSR build ----------------

__global__ void k_count(const int* __restrict__ dst1, const int* __restrict__ dst2,
                        int* __restrict__ cnt1, int* __restrict__ cnt2, int E) {
  int e = blockIdx.x * blockDim.x + threadIdx.x;
  if (e < E) {
    atomicAdd(&cnt1[dst1[e]], 1);
    atomicAdd(&cnt2[dst2[e]], 1);
  }
}

__global__ __launch_bounds__(1024) void k_scan(const int* __restrict__ cnt, int* __restrict__ rp, int n) {
  __shared__ int s[1024];
  int tid = threadIdx.x;
  int chunk = (n + 1023) >> 10;
  int beg = tid * chunk;
  int end = min(beg + chunk, n);
  int sum = 0;
  for (int i = beg; i < end; ++i) sum += cnt[i];
  s[tid] = sum;
  __syncthreads();
  for (int off = 1; off < 1024; off <<= 1) {
    int v = (tid >= off) ? s[tid - off] : 0;
    __syncthreads();
    s[tid] += v;
    __syncthreads();
  }
  int excl = (tid == 0) ? 0 : s[tid - 1];
  for (int i = beg; i < end; ++i) { rp[i] = excl; excl += cnt[i]; }
  if (tid == 1023) rp[n] = s[1023];
}

__global__ void k_scatter(const int* __restrict__ d1, const int* __restrict__ s1, const float* __restrict__ v1,
                          const int* __restrict__ rp1, int* __restrict__ cur1, int2* __restrict__ c1sv,
                          const int* __restrict__ s2, const int* __restrict__ d2,
                          const int* __restrict__ rp2, int* __restrict__ cur2,
                          int* __restrict__ c2s, int E) {
  int e = blockIdx.x * blockDim.x + threadIdx.x;
  if (e >= E) return;
  {
    int d = d1[e];
    int p = atomicAdd(&cur1[d], 1);
    c1sv[rp1[d] + p] = make_int2(s1[e], __float_as_int(v1[e]));
  }
  {
    int d = d2[e];
    int p = atomicAdd(&cur2[d], 1);
    c2s[rp2[d] + p] = s2[e];
  }
}

// ---------------- weight prep ----------------

__global__ void k_cvtgw(const float* __restrict__ W, unsigned short* __restrict__ Wb, int total) {
  int i = (blockIdx.x * blockDim.x + threadIdx.x) * 4;
  if (i + 3 < total) {
    float4 v = *(const float4*)(W + i);
    ushort4 o;
    o.x = f2b(v.x); o.y = f2b(v.y); o.z = f2b(v.z); o.w = f2b(v.w);
    *(ushort4*)(Wb + i) = o;
  }
}

// Pack weights into MFMA fragment order: frag(t,kf) at [(t*NKF+kf)*512 + lane*8 + j],
// value = W[k][nn] with k = kf*32 + (lane>>4)*8 + j, nn = t*16 + (lane&15).
__global__ void k_packw(const float* __restrict__ Wl, const float* __restrict__ Wr,
                        const float* __restrict__ W1, const float* __restrict__ W2,
                        unsigned short* __restrict__ Wlp, unsigned short* __restrict__ Wrp,
                        unsigned short* __restrict__ W1p, unsigned short* __restrict__ W2p) {
  int t = blockIdx.x * blockDim.x + threadIdx.x;
  if (t < 129024) {                         // Wl then Wr: 7 * 9216 each
    bool isR = t >= 64512;
    int u = isR ? t - 64512 : t;
    int i = u / 9216, v = u % 9216;
    int tt = v / 1536, r = v % 1536;
    int kf = r / 512, w = r % 512, l = w >> 3, j = w & 7;
    int c = l & 15, g = l >> 4;
    int k = kf * 32 + g * 8 + j, nn = tt * 16 + c;
    float val = (isR ? Wr : Wl)[i * 9216 + k * 96 + nn];
    (isR ? Wrp : Wlp)[u] = f2b(val);
  } else if (t < 147456) {                  // W1: 12t x 3kf
    int u = t - 129024;
    int tt = u / 1536, r = u % 1536;
    int kf = r / 512, w = r % 512, l = w >> 3, j = w & 7;
    int c = l & 15, g = l >> 4;
    int k = kf * 32 + g * 8 + j, nn = tt * 16 + c;
    W1p[u] = f2b(W1[k * 192 + nn]);
  } else if (t < 184320) {                  // W2: 12t x 6kf
    int u = t - 147456;
    int tt = u / 3072, r = u % 3072;
    int kf = r / 512, w = r % 512, l = w >> 3, j = w & 7;
    int c = l & 15, g = l >> 4;
    int k = kf * 32 + g * 8 + j, nn = tt * 16 + c;
    W2p[u] = f2b(W2[k * 192 + nn]);
  }
}

// ---------------- gc1: weighted SPMM + bias + relu + l2norm (unroll-4) ----------------

__global__ __launch_bounds__(256) void k_gc1(const int* __restrict__ rp, const int2* __restrict__ cv,
                                             const unsigned short* __restrict__ Wb,
                                             const float* __restrict__ b, unsigned short* __restrict__ out, int n) {
  int gw = (blockIdx.x * 256 + threadIdx.x) >> 6;
  int l = threadIdx.x & 63;
  if (gw >= n) return;
  int s = rp[gw], e = rp[gw + 1];
  bool act = l < 48;
  float a0 = 0.f, a1 = 0.f, b0 = 0.f, b1 = 0.f, c0 = 0.f, c1 = 0.f, d0 = 0.f, d1 = 0.f;
  int i = s;
  for (; i + 3 < e; i += 4) {
    int2 q0 = cv[i], q1 = cv[i + 1], q2 = cv[i + 2], q3 = cv[i + 3];
    if (act) {
      unsigned w0 = *(const unsigned*)(Wb + (size_t)q0.x * NH + 2 * l);
      unsigned w1 = *(const unsigned*)(Wb + (size_t)q1.x * NH + 2 * l);
      unsigned w2 = *(const unsigned*)(Wb + (size_t)q2.x * NH + 2 * l);
      unsigned w3 = *(const unsigned*)(Wb + (size_t)q3.x * NH + 2 * l);
      float v0 = __int_as_float(q0.y), v1 = __int_as_float(q1.y);
      float v2 = __int_as_float(q2.y), v3 = __int_as_float(q3.y);
      a0 = fmaf(v0, blo(w0), a0); a1 = fmaf(v0, bhi(w0), a1);
      b0 = fmaf(v1, blo(w1), b0); b1 = fmaf(v1, bhi(w1), b1);
      c0 = fmaf(v2, blo(w2), c0); c1 = fmaf(v2, bhi(w2), c1);
      d0 = fmaf(v3, blo(w3), d0); d1 = fmaf(v3, bhi(w3), d1);
    }
  }
  for (; i < e; ++i) {
    int2 q0 = cv[i];
    if (act) {
      unsigned w0 = *(const unsigned*)(Wb + (size_t)q0.x * NH + 2 * l);
      float v0 = __int_as_float(q0.y);
      a0 = fmaf(v0, blo(w0), a0); a1 = fmaf(v0, bhi(w0), a1);
    }
  }
  a0 += b0 + c0 + d0; a1 += b1 + c1 + d1;
  if (act) {
    a0 = fmaxf(a0 + b[2 * l], 0.f);
    a1 = fmaxf(a1 + b[2 * l + 1], 0.f);
  } else { a0 = a1 = 0.f; }
  float ss = a0 * a0 + a1 * a1;
#pragma unroll
  for (int o = 1; o < 64; o <<= 1) ss += __shfl_xor(ss, o);
  float sc = 1.f / fmaxf(sqrtf(ss), 1e-12f);
  if (act) {
    unsigned pk = ((unsigned)f2b(a1 * sc) << 16) | f2b(a0 * sc);
    ((unsigned*)out)[(size_t)gw * 48 + l] = pk;
  }
}

// ---------------- mean aggregation (unroll-4) — shared branch input ----------------

__global__ __launch_bounds__(256) void k_agg(const int* __restrict__ rp, const int* __restrict__ csrc,
                                             const unsigned short* __restrict__ X,
                                             unsigned short* __restrict__ out, int n) {
  int gw = (blockIdx.x * 256 + threadIdx.x) >> 6;
  int l = threadIdx.x & 63;
  if (gw >= n) return;
  int s = rp[gw], e = rp[gw + 1];
  bool act = l < 48;
  float a0 = 0.f, a1 = 0.f, b0 = 0.f, b1 = 0.f, c0 = 0.f, c1 = 0.f, d0 = 0.f, d1 = 0.f;
  int i = s;
  for (; i + 3 < e; i += 4) {
    int s0 = csrc[i], s1 = csrc[i + 1], s2 = csrc[i + 2], s3 = csrc[i + 3];
    if (act) {
      unsigned w0 = *(const unsigned*)(X + (size_t)s0 * NH + 2 * l);
      unsigned w1 = *(const unsigned*)(X + (size_t)s1 * NH + 2 * l);
      unsigned w2 = *(const unsigned*)(X + (size_t)s2 * NH + 2 * l);
      unsigned w3 = *(const unsigned*)(X + (size_t)s3 * NH + 2 * l);
      a0 += blo(w0); a1 += bhi(w0);
      b0 += blo(w1); b1 += bhi(w1);
      c0 += blo(w2); c1 += bhi(w2);
      d0 += blo(w3); d1 += bhi(w3);
    }
  }
  for (; i < e; ++i) {
    int s0 = csrc[i];
    if (act) {
      unsigned w0 = *(const unsigned*)(X + (size_t)s0 * NH + 2 * l);
      a0 += blo(w0); a1 += bhi(w0);
    }
  }
  a0 += b0 + c0 + d0; a1 += b1 + c1 + d1;
  float inv = 1.f / fmaxf((float)(e - s), 1.f);
  if (act) {
    unsigned pk = ((unsigned)f2b(a1 * inv) << 16) | f2b(a0 * inv);
    ((unsigned*)out)[(size_t)gw * 48 + l] = pk;
  }
}

// ---------------- trunk fused agg+SAGE (swapped operands, no LDS) ----------------
// mfma(W_frag, X_frag): output lane (c,g) holds Y[node=m0+c][n1=t*16+g*4+r].

template <int EPI>
__global__ __launch_bounds__(256) void k_sageagg(const int* __restrict__ rp, const int* __restrict__ csrc,
                                                 const unsigned short* __restrict__ X,
                                                 const unsigned short* __restrict__ Wlp,
                                                 const unsigned short* __restrict__ Wrp,
                                                 const float* __restrict__ bias,
                                                 unsigned short* __restrict__ Y, int n) {
  int wv = blockIdx.x * 4 + (threadIdx.x >> 6);
  int l = threadIdx.x & 63;
  int m0 = wv * 16;
  if (m0 >= n) return;
  int c = l & 15, g = l >> 4;
  int nd = min(m0 + c, n - 1);
  int s = rp[nd], e = rp[nd + 1];

  // gather-mean: lane (c,g) accumulates cols {kf*32+g*8 .. +8} of node nd
  float aa[3][8];
#pragma unroll
  for (int kf = 0; kf < 3; ++kf)
#pragma unroll
    for (int j = 0; j < 8; ++j) aa[kf][j] = 0.f;

  const unsigned short* Xg = X + g * 8;
  for (int i = s; i < e; ++i) {
    const unsigned short* xr = Xg + (size_t)csrc[i] * NH;
    short8 v0 = *(const short8*)(xr);
    short8 v1 = *(const short8*)(xr + 32);
    short8 v2 = *(const short8*)(xr + 64);
#pragma unroll
    for (int j = 0; j < 8; ++j) {
      aa[0][j] += b2f(v0[j]);
      aa[1][j] += b2f(v1[j]);
      aa[2][j] += b2f(v2[j]);
    }
  }
  float inv = 1.f / fmaxf((float)(e - s), 1.f);
  short8 af[3];
#pragma unroll
  for (int kf = 0; kf < 3; ++kf)
#pragma unroll
    for (int j = 0; j < 8; ++j) af[kf][j] = (short)f2b(aa[kf][j] * inv);

  size_t aoff = (size_t)nd * NH + g * 8;
  short8 xf[3];
#pragma unroll
  for (int kf = 0; kf < 3; ++kf) xf[kf] = *(const short8*)(X + aoff + kf * 32);

  f32x4 acc[6];
#pragma unroll
  for (int t = 0; t < 6; ++t) acc[t] = (f32x4){0.f, 0.f, 0.f, 0.f};
#pragma unroll
  for (int kf = 0; kf < 3; ++kf) {
#pragma unroll
    for (int t = 0; t < 6; ++t) {
      short8 wlf = *(const short8*)(Wlp + ((t * 3 + kf) << 9) + (l << 3));
      acc[t] = MFMA(wlf, af[kf], acc[t]);
    }
#pragma unroll
    for (int t = 0; t < 6; ++t) {
      short8 wrf = *(const short8*)(Wrp + ((t * 3 + kf) << 9) + (l << 3));
      acc[t] = MFMA(wrf, xf[kf], acc[t]);
    }
  }

  // epilogue: bias + relu (+l2norm over full row via 2 shfl_xor)
  float v[6][4];
  float ss = 0.f;
#pragma unroll
  for (int t = 0; t < 6; ++t) {
    float4 bv = *(const float4*)(bias + t * 16 + g * 4);
#pragma unroll
    for (int r = 0; r < 4; ++r) {
      float x = fmaxf(acc[t][r] + ((const float*)&bv)[r], 0.f);
      v[t][r] = x;
      ss = fmaf(x, x, ss);
    }
  }
  if (EPI == 0) {
    ss += __shfl_xor(ss, 16);
    ss += __shfl_xor(ss, 32);
    float sc = 1.f / fmaxf(sqrtf(ss), 1e-12f);
#pragma unroll
    for (int t = 0; t < 6; ++t)
#pragma unroll
      for (int r = 0; r < 4; ++r) v[t][r] *= sc;
  }
  if (m0 + c < n) {
    unsigned short* yr = Y + (size_t)(m0 + c) * NH;
#pragma unroll
    for (int t = 0; t < 6; ++t) {
      uint2 pk;
      pk.x = cvt_pk(v[t][0], v[t][1]);
      pk.y = cvt_pk(v[t][2], v[t][3]);
      *(uint2*)(yr + t * 16 + g * 4) = pk;
    }
  }
}

// ---------------- fused 3-layer MLP (swapped operands, no LDS): score += mlp(X) ----------------

__global__ __launch_bounds__(256) void k_mlp(const unsigned short* __restrict__ X,
                                             const unsigned short* __restrict__ W1p, const float* __restrict__ b1,
                                             const unsigned short* __restrict__ W2p, const float* __restrict__ b2,
                                             const float* __restrict__ W3, const float* __restrict__ b3,
                                             float* __restrict__ score, int n) {
  int wv = blockIdx.x * 4 + (threadIdx.x >> 6);
  int l = threadIdx.x & 63;
  int m0 = wv * 16;
  if (m0 >= n) return;
  int c = l & 15, g = l >> 4;
  int arow = min(m0 + c, n - 1);
  int srcA = c + ((g & 1) << 5), srcB = srcA + 16, hi = g >> 1;

  // MLP1: H[m=c][n1 regs]
  f32x4 acc1[12];
#pragma unroll
  for (int t = 0; t < 12; ++t) acc1[t] = (f32x4){0.f, 0.f, 0.f, 0.f};
#pragma unroll
  for (int kf = 0; kf < 3; ++kf) {
    short8 xf = *(const short8*)(X + (size_t)arow * NH + kf * 32 + g * 8);
#pragma unroll
    for (int t = 0; t < 12; ++t) {
      short8 wf = *(const short8*)(W1p + ((t * 3 + kf) << 9) + (l << 3));
      acc1[t] = MFMA(wf, xf, acc1[t]);
    }
  }
  unsigned pk1[12][2];
#pragma unroll
  for (int t = 0; t < 12; ++t) {
    float4 bv = *(const float4*)(b1 + t * 16 + g * 4);
    float h0 = fmaxf(acc1[t][0] + bv.x, 0.f);
    float h1 = fmaxf(acc1[t][1] + bv.y, 0.f);
    float h2 = fmaxf(acc1[t][2] + bv.z, 0.f);
    float h3 = fmaxf(acc1[t][3] + bv.w, 0.f);
    pk1[t][0] = cvt_pk(h0, h1);
    pk1[t][1] = cvt_pk(h2, h3);
  }

  // MLP2
  f32x4 acc2[12];
#pragma unroll
  for (int t = 0; t < 12; ++t) acc2[t] = (f32x4){0.f, 0.f, 0.f, 0.f};
#pragma unroll
  for (int kf = 0; kf < 6; ++kf) {
    short8 af = xchg(pk1[2 * kf][0], pk1[2 * kf][1], pk1[2 * kf + 1][0], pk1[2 * kf + 1][1], srcA, srcB, hi);
#pragma unroll
    for (int t = 0; t < 12; ++t) {
      short8 wf = *(const short8*)(W2p + ((t * 6 + kf) << 9) + (l << 3));
      acc2[t] = MFMA(wf, af, acc2[t]);
    }
  }

  // layer 3 dot + reduce over g
  float sv = 0.f;
#pragma unroll
  for (int t = 0; t < 12; ++t) {
    float4 bv = *(const float4*)(b2 + t * 16 + g * 4);
    float4 wv3 = *(const float4*)(W3 + t * 16 + g * 4);
#pragma unroll
    for (int r = 0; r < 4; ++r) {
      float h2 = fmaxf(acc2[t][r] + ((const float*)&bv)[r], 0.f);
      sv = fmaf(h2, ((const float*)&wv3)[r], sv);
    }
  }
  sv += __shfl_xor(sv, 16);
  sv += __shfl_xor(sv, 32);
  if (g == 0 && m0 + c < n) score[m0 + c] += sv + b3[0];
}

// ---------------- per-branch: sage -> l2norm -> 3-layer MLP -> atomic score (no LDS) ----------------

__global__ __launch_bounds__(256) void k_branch(const unsigned short* __restrict__ Ag,
                                                const unsigned short* __restrict__ X21,
                                                const unsigned short* __restrict__ Wlp,
                                                const unsigned short* __restrict__ Wrp,
                                                const float* __restrict__ sbl,
                                                const unsigned short* __restrict__ W1p, const float* __restrict__ b1,
                                                const unsigned short* __restrict__ W2p, const float* __restrict__ b2,
                                                const float* __restrict__ W3, const float* __restrict__ b3,
                                                unsigned short* __restrict__ Xb, float* __restrict__ score,
                                                int n, int gblk) {
  int bb = blockIdx.x / gblk;
  int blk = blockIdx.x - bb * gblk;
  int wid = threadIdx.x >> 6, l = threadIdx.x & 63;
  int m0 = (blk * 4 + wid) * 16;
  if (m0 >= n) return;
  int c = l & 15, g = l >> 4;
  int arow = min(m0 + c, n - 1);
  size_t aoff = (size_t)arow * NH + g * 8;
  int srcA = c + ((g & 1) << 5), srcB = srcA + 16, hi = g >> 1;

  const unsigned short* wl = Wlp + (size_t)bb * 9216;
  const unsigned short* wr = Wrp + (size_t)bb * 9216;
  const float* bl = sbl + (size_t)bb * NH;

  // ---- SAGE (swapped): Hs[m=c][n1 regs] ----
  f32x4 acc[6];
#pragma unroll
  for (int t = 0; t < 6; ++t) acc[t] = (f32x4){0.f, 0.f, 0.f, 0.f};
#pragma unroll
  for (int kf = 0; kf < 3; ++kf) {
    short8 agf = *(const short8*)(Ag + aoff + kf * 32);
    short8 xf = *(const short8*)(X21 + aoff + kf * 32);
#pragma unroll
    for (int t = 0; t < 6; ++t) {
      short8 wlf = *(const short8*)(wl + ((t * 3 + kf) << 9) + (l << 3));
      acc[t] = MFMA(wlf, agf, acc[t]);
    }
#pragma unroll
    for (int t = 0; t < 6; ++t) {
      short8 wrf = *(const short8*)(wr + ((t * 3 + kf) << 9) + (l << 3));
      acc[t] = MFMA(wrf, xf, acc[t]);
    }
  }
  // bias + relu + l2norm (row = lane c, reduce over g)
  float v[6][4];
  float ss = 0.f;
#pragma unroll
  for (int t = 0; t < 6; ++t) {
    float4 bv = *(const float4*)(bl + t * 16 + g * 4);
#pragma unroll
    for (int r = 0; r < 4; ++r) {
      float x = fmaxf(acc[t][r] + ((const float*)&bv)[r], 0.f);
      v[t][r] = x;
      ss = fmaf(x, x, ss);
    }
  }
  ss += __shfl_xor(ss, 16);
  ss += __shfl_xor(ss, 32);
  float sc = 1.f / fmaxf(sqrtf(ss), 1e-12f);

  unsigned pk[6][2];
#pragma unroll
  for (int t = 0; t < 6; ++t) {
    float x0 = v[t][0] * sc, x1 = v[t][1] * sc, x2 = v[t][2] * sc, x3 = v[t][3] * sc;
    pk[t][0] = cvt_pk(x0, x1);
    pk[t][1] = cvt_pk(x2, x3);
  }
  // branch 0 doubles as trunk layer-0 output
  if (bb == 0 && m0 + c < n) {
    unsigned short* yr = Xb + (size_t)(m0 + c) * NH;
#pragma unroll
    for (int t = 0; t < 6; ++t) *(uint2*)(yr + t * 16 + g * 4) = make_uint2(pk[t][0], pk[t][1]);
  }

  // ---- MLP1 ----
  f32x4 acc1[12];
#pragma unroll
  for (int t = 0; t < 12; ++t) acc1[t] = (f32x4){0.f, 0.f, 0.f, 0.f};
#pragma unroll
  for (int kf = 0; kf < 3; ++kf) {
    short8 af = xchg(pk[2 * kf][0], pk[2 * kf][1], pk[2 * kf + 1][0], pk[2 * kf + 1][1], srcA, srcB, hi);
#pragma unroll
    for (int t = 0; t < 12; ++t) {
      short8 wf = *(const short8*)(W1p + ((t * 3 + kf) << 9) + (l << 3));
      acc1[t] = MFMA(wf, af, acc1[t]);
    }
  }
  unsigned pk1[12][2];
#pragma unroll
  for (int t = 0; t < 12; ++t) {
    float4 bv = *(const float4*)(b1 + t * 16 + g * 4);
    float h0 = fmaxf(acc1[t][0] + bv.x, 0.f);
    float h1 = fmaxf(acc1[t][1] + bv.y, 0.f);
    float h2 = fmaxf(acc1[t][2] + bv.z, 0.f);
    float h3 = fmaxf(acc1[t][3] + bv.w, 0.f);
    pk1[t][0] = cvt_pk(h0, h1);
    pk1[t][1] = cvt_pk(h2, h3);
  }

  // ---- MLP2 ----
  f32x4 acc2[12];
#pragma unroll
  for (int t = 0; t < 12; ++t) acc2[t] = (f32x4){0.f, 0.f, 0.f, 0.f};
#pragma unroll
  for (int kf = 0; kf < 6; ++kf) {
    short8 af = xchg(pk1[2 * kf][0], pk1[2 * kf][1], pk1[2 * kf + 1][0], pk1[2 * kf + 1][1], srcA, srcB, hi);
#pragma unroll
    for (int t = 0; t < 12; ++t) {
      short8 wf = *(const short8*)(W2p + ((t * 6 + kf) << 9) + (l << 3));
      acc2[t] = MFMA(wf, af, acc2[t]);
    }
  }

  // ---- layer 3 dot + reduce + atomic ----
  float sv = 0.f;
#pragma unroll
  for (int t = 0; t < 12; ++t) {
    float4 bv = *(const float4*)(b2 + t * 16 + g * 4);
    float4 wv3 = *(const float4*)(W3 + t * 16 + g * 4);
#pragma unroll
    for (int r = 0; r < 4; ++r) {
      float h2 = fmaxf(acc2[t][r] + ((const float*)&bv)[r], 0.f);
      sv = fmaf(h2, ((const float*)&wv3)[r], sv);
    }
  }
  sv += __shfl_xor(sv, 16);
  sv += __shfl_xor(sv, 32);
  if (g == 0 && m0 + c < n) atomicAdd(&score[m0 + c], sv + b3[0]);
}

// ---------------- host ----------------

extern "C" void kernel_launch(void* const* d_in, const int* in_sizes, int n_in,
                              void* d_out, int out_size, void* d_ws, size_t ws_size,
                              hipStream_t stream) {
  const int* ei1 = (const int*)d_in[0];
  const float* ev1 = (const float*)d_in[1];
  const int* ei2 = (const int*)d_in[2];
  const float* gW = (const float*)d_in[3];
  const float* gb = (const float*)d_in[4];
  const float* sWl = (const float*)d_in[5];
  const float* sbl = (const float*)d_in[6];
  const float* sWr = (const float*)d_in[7];
  const float* W1 = (const float*)d_in[8];
  const float* b1 = (const float*)d_in[9];
  const float* W2 = (const float*)d_in[10];
  const float* b2 = (const float*)d_in[11];
  const float* W3 = (const float*)d_in[12];
  const float* b3 = (const float*)d_in[13];
  float* score = (float*)d_out;

  const int E = in_sizes[0] / 2;
  const int n = in_sizes[3] / NH;

  const int* d1 = ei1;      // edge_index1[0] = dst
  const int* s1 = ei1 + E;  // edge_index1[1] = src
  const int* s2 = ei2;      // edge_index2[0] = src
  const int* d2 = ei2 + E;  // edge_index2[1] = dst

  char* w = (char*)d_ws;
  auto alloc = [&](size_t bytes) {
    char* p = w;
    w += (bytes + 255) & ~(size_t)255;
    return p;
  };
  int* cnt1 = (int*)alloc((size_t)n * 4);
  int* cnt2 = (int*)alloc((size_t)n * 4);
  int* cur1 = (int*)alloc((size_t)n * 4);
  int* cur2 = (int*)alloc((size_t)n * 4);
  int* rp1 = (int*)alloc((size_t)(n + 1) * 4);
  int* rp2 = (int*)alloc((size_t)(n + 1) * 4);
  int2* c1sv = (int2*)alloc((size_t)E * 8);
  int* c2s = (int*)alloc((size_t)E * 4);
  unsigned short* gwb = (unsigned short*)alloc((size_t)n * NH * 2);
  unsigned short* wlp = (unsigned short*)alloc((size_t)7 * NH * NH * 2);
  unsigned short* wrp = (unsigned short*)alloc((size_t)7 * NH * NH * 2);
  unsigned short* w1p = (unsigned short*)alloc((size_t)NH * NH2 * 2);
  unsigned short* w2p = (unsigned short*)alloc((size_t)NH2 * NH2 * 2);
  unsigned short* x21 = (unsigned short*)alloc((size_t)n * NH * 2);
  unsigned short* Ag = (unsigned short*)alloc((size_t)n * NH * 2);
  unsigned short* xb = (unsigned short*)alloc((size_t)n * NH * 2);
  unsigned short* tb = (unsigned short*)alloc((size_t)n * NH * 2);

  size_t zbytes = (size_t)((char*)cur2 - (char*)cnt1) + (size_t)n * 4;
  hipMemsetAsync(cnt1, 0, zbytes, stream);
  hipMemsetAsync(score, 0, (size_t)n * 4, stream);

  int eb = (E + 255) / 256;
  int nb4 = (n + 3) / 4;          // wave-per-node kernels
  int gblk = (n + 63) / 64;       // 4 MFMA waves (16 rows each) per block

  k_count<<<eb, 256, 0, stream>>>(d1, d2, cnt1, cnt2, E);
  k_scan<<<1, 1024, 0, stream>>>(cnt1, rp1, n);
  k_scan<<<1, 1024, 0, stream>>>(cnt2, rp2, n);
  k_scatter<<<eb, 256, 0, stream>>>(d1, s1, ev1, rp1, cur1, c1sv, s2, d2, rp2, cur2, c2s, E);

  k_cvtgw<<<(n * NH / 4 + 255) / 256, 256, 0, stream>>>(gW, gwb, n * NH);
  k_packw<<<720, 256, 0, stream>>>(sWl, sWr, W1, W2, wlp, wrp, w1p, w2p);

  // x2_1 = l2norm(relu(spmm(adj1, gc1_W) + gc1_b))
  k_gc1<<<nb4, 256, 0, stream>>>(rp1, c1sv, gwb, gb, x21, n);

  // score += mlp(x2_1)
  k_mlp<<<gblk, 256, 0, stream>>>(x21, w1p, b1, w2p, b2, W3, b3, score, n);

  // Ag = mean-agg(x2_1) — shared by all 6 score branches (incl. trunk layer 0)
  k_agg<<<nb4, 256, 0, stream>>>(rp2, c2s, x21, Ag, n);

  // 6 score branches, one per grid slice (branch 0 emits xb = trunk layer-0 out)
  k_branch<<<6 * gblk, 256, 0, stream>>>(Ag, x21, wlp, wrp, sbl, w1p, b1, w2p, b2, W3, b3,
                                         xb, score, n, gblk);

  // trunk layers 1..5 (fused agg+sage)
  unsigned short* xc = xb;
  unsigned short* xn = tb;
  for (int i = 1; i < 6; ++i) {
    k_sageagg<0><<<gblk, 256, 0, stream>>>(rp2, c2s, xc, wlp + (size_t)i * 9216,
                                           wrp + (size_t)i * 9216, sbl + (size_t)i * NH, xn, n);
    unsigned short* tmp = xc; xc = xn; xn = tmp;
  }

  // last layer: relu only, then final mlp
  k_sageagg<1><<<gblk, 256, 0, stream>>>(rp2, c2s, xc, wlp + (size_t)6 * 9216,
                                         wrp + (size_t)6 * 9216, sbl + (size_t)6 * NH, xn, n);
  k_mlp<<<gblk, 256, 0, stream>>>(xn, w1p, b1, w2p, b2, W3, b3, score, n);

  (void)n_in; (void)out_size; (void)ws_size;
}